// Round 4
// baseline (704.763 us; speedup 1.0000x reference)
//
#include <hip/hip_runtime.h>
#include <hip/hip_bf16.h>
#include <hip/hip_cooperative_groups.h>

namespace cg = cooperative_groups;

// ---------------------------------------------------------------------------
// DRRGHead as ONE persistent cooperative kernel (12 phases, grid.sync between).
//   relu(cat(x, A@x) @ W + b)  ==  relu(x@W_top + b  +  A @ (x@W_bot))
// Phase 0: bn_stats || weight repack || 1x1 conv   (independent work pools)
// Phase 1a/1b: two-step BN reduction; Phase 2: bn apply -> bf16 x0
// Phases 3..9: GEMM_l (128x128 MFMA tile, 2-phase dbuf global_load_lds)
//              alternating with fused agg epilogues y = relu(P_L + A@P_R)
// Phase 10: layer-4 agg + knn gather + MLP classifier (1 graph/block).
// Rationale: ~8-10us per dispatch boundary x 14 dispatches dominated runtime.
// ---------------------------------------------------------------------------

using f32x4 = __attribute__((ext_vector_type(4))) float;
using s16x8 = __attribute__((ext_vector_type(8))) short;   // 8 bf16

#define GN 20992          // G*N rows (= 164*128 exactly)
#define NFEAT 576
#define NGRAPH 512
#define NNODE 41
#define NTM 164           // m-tiles of 128

typedef __attribute__((address_space(1))) const unsigned int gas_u32;
typedef __attribute__((address_space(3))) unsigned int las_u32;

__device__ __forceinline__ void gl_lds16(const void* g, void* l) {
  __builtin_amdgcn_global_load_lds((gas_u32*)g, (las_u32*)l, 16, 0, 0);
}

struct MegaArgs {
  const float* inputs; const float* conv_w; const float* conv_b;
  const float* node_feats; const float* Aadj; const int* knn;
  const float* W1; const float* W2; const float* W3; const float* W4;
  const float* b1; const float* b2; const float* b3; const float* b4;
  const float* cls_w1; const float* cls_b1; const float* prelu_a;
  const float* cls_w2; const float* cls_b2;
  __hip_bfloat16* B1t; __hip_bfloat16* B2t; __hip_bfloat16* B3t; __hip_bfloat16* B4t;
  float* partial; float* partial2; float* stats;
  __hip_bfloat16* R1; __hip_bfloat16* R2;
  float* out;
};

// ---------------- phase 0a: BN stats (512 units x 41 rows) ------------------
__device__ __forceinline__ void stats_phase(const MegaArgs& a) {
  for (int u = blockIdx.x; u < 512; u += gridDim.x) {
    int r0 = u * NNODE;
    for (int c = threadIdx.x; c < NFEAT; c += 256) {
      float s = 0.f, s2 = 0.f;
#pragma unroll 1
      for (int r = 0; r < NNODE; ++r) {
        float v = a.node_feats[(size_t)(r0 + r) * NFEAT + c];
        s += v; s2 += v * v;
      }
      a.partial[(size_t)u * 1152 + c] = s;
      a.partial[(size_t)u * 1152 + NFEAT + c] = s2;
    }
  }
}

// ---------------- phase 0b: weight repack W(2K x N) f32 -> Bt(2N x K) bf16 --
__device__ __forceinline__ void wt_phase(const MegaArgs& a, char* smem) {
  float* T = (float*)smem;   // [32][33]
  for (int u = blockIdx.x; u < 912; u += gridDim.x) {
    const float* W; __hip_bfloat16* B; int K, N, t;
    if (u < 576)      { W = a.W1; B = a.B1t; K = 576; N = 512; t = u; }
    else if (u < 832) { W = a.W2; B = a.B2t; K = 512; N = 256; t = u - 576; }
    else if (u < 896) { W = a.W3; B = a.B3t; K = 256; N = 128; t = u - 832; }
    else              { W = a.W4; B = a.B4t; K = 128; N = 64;  t = u - 896; }
    int tilesN = N >> 5;
    int perhalf = (K >> 5) * tilesN;
    int h = t / perhalf; t -= h * perhalf;
    int tk = t / tilesN, tn = t - tk * tilesN;
    int r = threadIdx.x >> 5, cc = threadIdx.x & 31;
    const float* Wh = W + (size_t)h * K * N;
    __syncthreads();
#pragma unroll
    for (int i = 0; i < 4; ++i)
      T[(r + i * 8) * 33 + cc] = Wh[(size_t)(tk * 32 + r + i * 8) * N + tn * 32 + cc];
    __syncthreads();
    __hip_bfloat16* Bh = B + (size_t)h * N * K;
#pragma unroll
    for (int i = 0; i < 4; ++i)
      Bh[(size_t)(tn * 32 + r + i * 8) * K + tk * 32 + cc] =
          __float2bfloat16(T[cc * 33 + r + i * 8]);
  }
}

// ---------------- phase 0c: 1x1 conv ----------------------------------------
__device__ __forceinline__ void conv_phase(const MegaArgs& a) {
  for (int u = blockIdx.x; u < 1024; u += gridDim.x) {
    int p = u * 256 + threadIdx.x;
    int img = p >> 16, q = p & 65535;
    const float4* ip = (const float4*)a.inputs + (size_t)img * 32 * 65536 + q;
    float4 acc[6];
#pragma unroll
    for (int o = 0; o < 6; ++o) { float b0 = a.conv_b[o]; acc[o] = make_float4(b0, b0, b0, b0); }
#pragma unroll 4
    for (int c = 0; c < 32; ++c) {
      float4 x = ip[(size_t)c * 65536];
#pragma unroll
      for (int o = 0; o < 6; ++o) {
        float wv = a.conv_w[o * 32 + c];
        acc[o].x += x.x * wv; acc[o].y += x.y * wv;
        acc[o].z += x.z * wv; acc[o].w += x.w * wv;
      }
    }
    float4* op = (float4*)a.out + (size_t)img * 6 * 65536 + q;
#pragma unroll
    for (int o = 0; o < 6; ++o) op[(size_t)o * 65536] = acc[o];
  }
}

// ---------------- phase 1a/1b: BN reduce ------------------------------------
__device__ __forceinline__ void reduceA_phase(const MegaArgs& a) {
  for (int u = blockIdx.x; u < 72; u += gridDim.x) {
    int gid = u * 256 + threadIdx.x;          // 18432 = 1152 cols x 16 groups
    int col = gid % 1152, grp = gid / 1152;
    float s = 0.f;
#pragma unroll 8
    for (int q = 0; q < 32; ++q)
      s += a.partial[(size_t)(grp * 32 + q) * 1152 + col];
    a.partial2[(size_t)grp * 1152 + col] = s;
  }
}

__device__ __forceinline__ void reduceB_phase(const MegaArgs& a) {
  int gid = blockIdx.x * 256 + threadIdx.x;
  if (gid < NFEAT) {
    float s = 0.f, s2 = 0.f;
#pragma unroll
    for (int grp = 0; grp < 16; ++grp) {
      s += a.partial2[(size_t)grp * 1152 + gid];
      s2 += a.partial2[(size_t)grp * 1152 + NFEAT + gid];
    }
    float m = s * (1.f / GN);
    float v = s2 * (1.f / GN) - m * m;
    a.stats[gid] = m;
    a.stats[NFEAT + gid] = rsqrtf(v + 1e-5f);
  }
}

// ---------------- phase 2: BN apply -> bf16 x0 (20992 x 576) ----------------
__device__ __forceinline__ void apply_phase(const MegaArgs& a) {
  for (int u = blockIdx.x; u < 5904; u += gridDim.x) {
    int idx = u * 256 + threadIdx.x;
    int f0 = (idx * 8) % NFEAT;               // 576 % 8 == 0
    const float* src = a.node_feats + (size_t)idx * 8;
    float4 p0 = *(const float4*)src, p1 = *(const float4*)(src + 4);
    float vv[8] = {p0.x, p0.y, p0.z, p0.w, p1.x, p1.y, p1.z, p1.w};
    __hip_bfloat16 o[8];
#pragma unroll
    for (int j = 0; j < 8; ++j) {
      float m = a.stats[f0 + j], inv = a.stats[NFEAT + f0 + j];
      o[j] = __float2bfloat16((vv[j] - m) * inv);
    }
    *(uint4*)&a.R1[(size_t)idx * 8] = *(const uint4*)o;
  }
}

// ---------------- GEMM phase: P = x @ Bt^T (+bias on cols < biasN) ----------
// 128x128 tile, 4 waves 2x2, 2-phase double-buffered LDS (BK=32).
__device__ __forceinline__ void gemm_phase(
    char* smem, const __hip_bfloat16* X, const __hip_bfloat16* Bt,
    const float* bias, int biasN, __hip_bfloat16* P, int Np, int K, int NTN) {
  short* Ash = (short*)smem;            // [2][128*32]
  short* Bsh = (short*)(smem + 16384);
  int tid = threadIdx.x;
  int wave = tid >> 6, lane = tid & 63;
  int wm = wave >> 1, wn = wave & 1;
  int lr = lane & 15, kb = lane >> 4;
  int c0 = tid, c1 = tid + 256;
  int ar0 = c0 >> 2, ac0 = (c0 & 3) * 8;
  int ar1 = c1 >> 2, ac1 = (c1 & 3) * 8;
  int nTiles = NTM * NTN;

  for (int t = blockIdx.x; t < nTiles; t += gridDim.x) {
    int sg = t / (NTN * 8);
    int rem = t - sg * (NTN * 8);
    int Wm = NTM - sg * 8; if (Wm > 8) Wm = 8;
    int mt = sg * 8 + rem % Wm;
    int nt = rem / Wm;
    int m0 = mt * 128, n0 = nt * 128;

    f32x4 acc[4][4];
#pragma unroll
    for (int m = 0; m < 4; ++m)
#pragma unroll
      for (int n = 0; n < 4; ++n) acc[m][n] = (f32x4){0.f, 0.f, 0.f, 0.f};

    const short* Ag = (const short*)X + (size_t)m0 * K;
    const short* Bg = (const short*)Bt + (size_t)n0 * K;

    __syncthreads();   // prev tile's LDS consumers done
    gl_lds16(Ag + (size_t)ar0 * K + ac0, &Ash[c0 * 8]);
    gl_lds16(Ag + (size_t)ar1 * K + ac1, &Ash[c1 * 8]);
    gl_lds16(Bg + (size_t)ar0 * K + ac0, &Bsh[c0 * 8]);
    gl_lds16(Bg + (size_t)ar1 * K + ac1, &Bsh[c1 * 8]);
    __syncthreads();   // vmcnt drained -> tile 0 resident

    int nkt = K >> 5;
    int cur = 0;
    for (int kt = 0; kt < nkt; ++kt) {
      if (kt + 1 < nkt) {
        int k1 = (kt + 1) * 32;
        int nxt = (cur ^ 1) * 4096;
        gl_lds16(Ag + (size_t)ar0 * K + k1 + ac0, &Ash[nxt + c0 * 8]);
        gl_lds16(Ag + (size_t)ar1 * K + k1 + ac1, &Ash[nxt + c1 * 8]);
        gl_lds16(Bg + (size_t)ar0 * K + k1 + ac0, &Bsh[nxt + c0 * 8]);
        gl_lds16(Bg + (size_t)ar1 * K + k1 + ac1, &Bsh[nxt + c1 * 8]);
      }
      int cb = cur * 4096;
      s16x8 af[4], bfr[4];
#pragma unroll
      for (int m = 0; m < 4; ++m)
        af[m] = *(const s16x8*)&Ash[cb + (wm * 64 + m * 16 + lr) * 32 + kb * 8];
#pragma unroll
      for (int n = 0; n < 4; ++n)
        bfr[n] = *(const s16x8*)&Bsh[cb + (wn * 64 + n * 16 + lr) * 32 + kb * 8];
#pragma unroll
      for (int m = 0; m < 4; ++m)
#pragma unroll
        for (int n = 0; n < 4; ++n)
          acc[m][n] = __builtin_amdgcn_mfma_f32_16x16x32_bf16(af[m], bfr[n], acc[m][n], 0, 0, 0);
      __syncthreads();
      cur ^= 1;
    }

    int rbase = (lane >> 4) * 4;
#pragma unroll
    for (int m = 0; m < 4; ++m) {
      int row = m0 + wm * 64 + m * 16 + rbase;
#pragma unroll
      for (int n = 0; n < 4; ++n) {
        int col = n0 + wn * 64 + n * 16 + lr;
        float bv = (col < biasN) ? bias[col] : 0.f;
#pragma unroll
        for (int r = 0; r < 4; ++r) {
          float v = acc[m][n][r] + bv;
          P[(size_t)(row + r) * Np + col] = __float2bfloat16(v);
        }
      }
    }
  }
}

// ---------------- agg phase: y = relu(P_L + A @ P_R), layers 1-3 ------------
template <int N>
__device__ __forceinline__ void aggep_phase(
    char* smem, const __hip_bfloat16* P, const float* Aadj, __hip_bfloat16* Y) {
  constexpr int GPB = (N >= 256) ? 1 : (256 / N);
  float* Ash = (float*)smem;
  for (int u = blockIdx.x; u < NGRAPH / GPB; u += gridDim.x) {
    int g0 = u * GPB;
    __syncthreads();
    for (int i = threadIdx.x; i < GPB * NNODE * NNODE; i += 256)
      Ash[i] = Aadj[(size_t)g0 * (NNODE * NNODE) + i];
    __syncthreads();
    int sub, c;
    if constexpr (GPB == 1) { sub = 0; c = threadIdx.x; }
    else { sub = threadIdx.x / N; c = threadIdx.x % N; }
    const float* Am = &Ash[sub * NNODE * NNODE];
    const __hip_bfloat16* Pg = P + (size_t)(g0 + sub) * NNODE * (2 * N);
    __hip_bfloat16* Yg = Y + (size_t)(g0 + sub) * NNODE * N;
    for (; c < N; c += 256) {
      float pr[NNODE];
#pragma unroll
      for (int m = 0; m < NNODE; ++m)
        pr[m] = __bfloat162float(Pg[(size_t)m * (2 * N) + N + c]);
#pragma unroll 1
      for (int n = 0; n < NNODE; ++n) {
        float aa = __bfloat162float(Pg[(size_t)n * (2 * N) + c]);
#pragma unroll
        for (int m = 0; m < NNODE; ++m) aa += Am[n * NNODE + m] * pr[m];
        aa = aa > 0.f ? aa : 0.f;
        Yg[(size_t)n * N + c] = __float2bfloat16(aa);
      }
      if constexpr (GPB > 1) break;
    }
  }
}

// ---------------- phase 10: layer-4 agg + knn gather + classifier -----------
__device__ __forceinline__ void aggcls_phase(char* smem, const MegaArgs& a) {
  float* Ash = (float*)smem;          // 1681
  float* Ysh = Ash + 1681;            // 41*64 = 2624
  float* Wsh = Ysh + 2624;            // 2048
  float* cb  = Wsh + 2048;            // 130  -> total 25932 B
  int tid = threadIdx.x;
  for (int i = tid; i < 2048; i += 256) Wsh[i] = a.cls_w1[i];
  if (tid < 32) { cb[tid] = a.cls_b1[tid]; cb[32 + tid] = a.prelu_a[tid]; }
  if (tid < 64) cb[64 + tid] = a.cls_w2[tid];
  if (tid < 2) cb[128 + tid] = a.cls_b2[tid];
  const __hip_bfloat16* P = a.R2;
  for (int g = blockIdx.x; g < NGRAPH; g += gridDim.x) {
    __syncthreads();   // Wsh ready (1st iter) / prev iter users done
    for (int i = tid; i < NNODE * NNODE; i += 256)
      Ash[i] = a.Aadj[(size_t)g * (NNODE * NNODE) + i];
    __syncthreads();
    int c = tid & 63, quarter = tid >> 6;
    const __hip_bfloat16* Pg = P + (size_t)g * NNODE * 128;
    float pr[NNODE];
#pragma unroll
    for (int m = 0; m < NNODE; ++m)
      pr[m] = __bfloat162float(Pg[(size_t)m * 128 + 64 + c]);
#pragma unroll 1
    for (int n = quarter; n < NNODE; n += 4) {
      float aa = __bfloat162float(Pg[(size_t)n * 128 + c]);
#pragma unroll
      for (int m = 0; m < NNODE; ++m) aa += Ash[n * NNODE + m] * pr[m];
      Ysh[n * 64 + c] = aa > 0.f ? aa : 0.f;
    }
    __syncthreads();
    // classifier: 8 edges x 32 lanes
    int el = tid >> 5, j = tid & 31;
    int e = g * 8 + el;
    int node = a.knn[e];
    const float* fp = &Ysh[node * 64];
    float acc = cb[j];
#pragma unroll
    for (int d = 0; d < 64; ++d) acc += fp[d] * Wsh[d * 32 + j];
    float h = acc >= 0.f ? acc : cb[32 + j] * acc;
#pragma unroll
    for (int o = 0; o < 2; ++o) {
      float v = h * cb[64 + j * 2 + o];
      v += __shfl_xor(v, 16, 32); v += __shfl_xor(v, 8, 32);
      v += __shfl_xor(v, 4, 32);  v += __shfl_xor(v, 2, 32);
      v += __shfl_xor(v, 1, 32);
      if (j == 0) a.out[6291456 + (size_t)e * 2 + o] = v;
    }
  }
}

// ---------------- the mega kernel -------------------------------------------
__global__ __launch_bounds__(256, 3) void mega_kernel(MegaArgs a) {
  __shared__ __align__(16) char smem[32768];
  cg::grid_group grid = cg::this_grid();

  stats_phase(a);
  wt_phase(a, smem);
  conv_phase(a);
  grid.sync();
  reduceA_phase(a);
  grid.sync();
  reduceB_phase(a);
  grid.sync();
  apply_phase(a);
  grid.sync();
  // L1: P1 = x0(20992x576) @ B1t(1024x576)^T
  gemm_phase(smem, a.R1, a.B1t, a.b1, 512, a.R2, 1024, 576, 8);
  grid.sync();
  aggep_phase<512>(smem, a.R2, a.Aadj, a.R1);
  grid.sync();
  gemm_phase(smem, a.R1, a.B2t, a.b2, 256, a.R2, 512, 512, 4);
  grid.sync();
  aggep_phase<256>(smem, a.R2, a.Aadj, a.R1);
  grid.sync();
  gemm_phase(smem, a.R1, a.B3t, a.b3, 128, a.R2, 256, 256, 2);
  grid.sync();
  aggep_phase<128>(smem, a.R2, a.Aadj, a.R1);
  grid.sync();
  gemm_phase(smem, a.R1, a.B4t, a.b4, 64, a.R2, 128, 128, 1);
  grid.sync();
  aggcls_phase(smem, a);
}

// ---------------------------------------------------------------------------
extern "C" void kernel_launch(void* const* d_in, const int* in_sizes, int n_in,
                              void* d_out, int out_size, void* d_ws, size_t ws_size,
                              hipStream_t stream) {
  char* ws = (char*)d_ws;
  char* R1 = ws;                        // x0 (24.2 MB) / x1 / x2 / x3
  char* R2 = ws + 24200192;             // P1 (43.0 MB) / P2 / P3 / P4
  char* wp = ws + 24200192 + 42991616;

  MegaArgs a;
  a.inputs     = (const float*)d_in[0];
  a.node_feats = (const float*)d_in[1];
  a.Aadj       = (const float*)d_in[2];
  a.knn        = (const int*)d_in[3];
  a.conv_w     = (const float*)d_in[4];
  a.conv_b     = (const float*)d_in[5];
  a.W1 = (const float*)d_in[6];  a.b1 = (const float*)d_in[7];
  a.W2 = (const float*)d_in[8];  a.b2 = (const float*)d_in[9];
  a.W3 = (const float*)d_in[10]; a.b3 = (const float*)d_in[11];
  a.W4 = (const float*)d_in[12]; a.b4 = (const float*)d_in[13];
  a.cls_w1 = (const float*)d_in[14]; a.cls_b1 = (const float*)d_in[15];
  a.prelu_a = (const float*)d_in[16];
  a.cls_w2 = (const float*)d_in[17]; a.cls_b2 = (const float*)d_in[18];
  a.B1t = (__hip_bfloat16*)wp;            wp += 1179648;    // 1024 x 576
  a.B2t = (__hip_bfloat16*)wp;            wp += 524288;     // 512 x 512
  a.B3t = (__hip_bfloat16*)wp;            wp += 131072;     // 256 x 256
  a.B4t = (__hip_bfloat16*)wp;            wp += 32768;      // 128 x 128
  a.partial  = (float*)wp;                wp += 512 * 1152 * 4;
  a.partial2 = (float*)wp;                wp += 16 * 1152 * 4;
  a.stats    = (float*)wp;                wp += 1152 * 4;
  a.R1 = (__hip_bfloat16*)R1;
  a.R2 = (__hip_bfloat16*)R2;
  a.out = (float*)d_out;

  int nb = 0;
  if (hipOccupancyMaxActiveBlocksPerMultiprocessor(
          &nb, (const void*)mega_kernel, 256, 0) != hipSuccess || nb < 1)
    nb = 2;
  int grid = nb * 256;
  if (grid > 1312) grid = 1312;

  void* args[] = { (void*)&a };
  hipLaunchCooperativeKernel((const void*)mega_kernel, dim3(grid), dim3(256),
                             args, 0, stream);
}

// Round 6
// 390.591 us; speedup vs baseline: 1.8043x; 1.8043x over previous
//
#include <hip/hip_runtime.h>
#include <hip/hip_bf16.h>

// ---------------------------------------------------------------------------
// DRRGHead, 10 regular dispatches (cooperative grid.sync proved ~25us/sync).
//   relu(cat(x_norm, A@x_norm) @ W + b) == relu(x@W' + b' + A@(x@W'_bot))
// with BN folded into W1 (rows scaled by inv) and bias (cvec; A row-sums = 1
// pass the constant through the mean-aggregation).
// K1 front: conv || bn-stats || bf16-cast || repack W2-4   (block pools)
// K2: wide bn-reduce -> inv, m*inv
// K3: W1 fold-repack (576 tiles) + cvec GEMV (4 blocks)
// G1,A1,G2,A2,G3,A3: MFMA GEMM (128x128, 2-ph dbuf global_load_lds,
//                    XCD supergroup swizzle) + fused agg epilogue
// G4F: gemm4 + agg4 + knn classifier fused, P in LDS only (3 graphs/block).
// ---------------------------------------------------------------------------

using f32x4 = __attribute__((ext_vector_type(4))) float;
using s16x8 = __attribute__((ext_vector_type(8))) short;   // 8 bf16

#define GN 20992          // G*N rows (= 164*128 exactly)
#define NFEAT 576
#define NGRAPH 512
#define NNODE 41
#define NTM 164           // m-tiles of 128

typedef __attribute__((address_space(1))) const unsigned int gas_u32;
typedef __attribute__((address_space(3))) unsigned int las_u32;

__device__ __forceinline__ void gl_lds16(const void* g, void* l) {
  __builtin_amdgcn_global_load_lds((gas_u32*)g, (las_u32*)l, 16, 0, 0);
}

// ---------------- K1: front (conv || stats || cast || wt2-4 pools) ----------
__global__ __launch_bounds__(256) void front_kernel(
    const float* __restrict__ inputs, const float* __restrict__ conv_w,
    const float* __restrict__ conv_b, const float* __restrict__ nf,
    const float* __restrict__ W2, const float* __restrict__ W3,
    const float* __restrict__ W4,
    float* __restrict__ out, float* __restrict__ partial,
    __hip_bfloat16* __restrict__ x0,
    __hip_bfloat16* __restrict__ B2, __hip_bfloat16* __restrict__ B3,
    __hip_bfloat16* __restrict__ B4) {
  __shared__ float T[32 * 33];
  int b = blockIdx.x;
  int tid = threadIdx.x;
  if (b < 1024) {                       // ---- conv pool
    int p = b * 256 + tid;
    int img = p >> 16, q = p & 65535;
    const float4* ip = (const float4*)inputs + (size_t)img * 32 * 65536 + q;
    float4 acc[6];
#pragma unroll
    for (int o = 0; o < 6; ++o) { float b0 = conv_b[o]; acc[o] = make_float4(b0, b0, b0, b0); }
#pragma unroll 4
    for (int c = 0; c < 32; ++c) {
      float4 x = ip[(size_t)c * 65536];
#pragma unroll
      for (int o = 0; o < 6; ++o) {
        float wv = conv_w[o * 32 + c];
        acc[o].x += x.x * wv; acc[o].y += x.y * wv;
        acc[o].z += x.z * wv; acc[o].w += x.w * wv;
      }
    }
    float4* op = (float4*)out + (size_t)img * 6 * 65536 + q;
#pragma unroll
    for (int o = 0; o < 6; ++o) op[(size_t)o * 65536] = acc[o];
  } else if (b < 6928) {                // ---- bf16 cast pool (raw x)
    int idx = (b - 1024) * 256 + tid;   // 8-elem chunk
    const float* src = nf + (size_t)idx * 8;
    float4 p0 = *(const float4*)src, p1 = *(const float4*)(src + 4);
    float vv[8] = {p0.x, p0.y, p0.z, p0.w, p1.x, p1.y, p1.z, p1.w};
    __hip_bfloat16 o[8];
#pragma unroll
    for (int j = 0; j < 8; ++j) o[j] = __float2bfloat16(vv[j]);
    *(uint4*)&x0[(size_t)idx * 8] = *(const uint4*)o;
  } else if (b < 7184) {                // ---- bn stats pool
    int u = b - 6928;                   // 256 units x 82 rows
    int r0 = u * 82;
    for (int c = tid; c < NFEAT; c += 256) {
      float s = 0.f, s2 = 0.f;
#pragma unroll 1
      for (int r = 0; r < 82; ++r) {
        float v = nf[(size_t)(r0 + r) * NFEAT + c];
        s += v; s2 += v * v;
      }
      partial[(size_t)u * 1152 + c] = s;
      partial[(size_t)u * 1152 + NFEAT + c] = s2;
    }
  } else {                              // ---- wt repack pool (W2, W3, W4)
    int u = b - 7184;
    const float* W; __hip_bfloat16* B; int K, N, t;
    if (u < 256)      { W = W2; B = B2; K = 512; N = 256; t = u; }
    else if (u < 320) { W = W3; B = B3; K = 256; N = 128; t = u - 256; }
    else              { W = W4; B = B4; K = 128; N = 64;  t = u - 320; }
    int tilesN = N >> 5;
    int perhalf = (K >> 5) * tilesN;
    int h = t / perhalf; t -= h * perhalf;
    int tk = t / tilesN, tn = t - tk * tilesN;
    int r = tid >> 5, cc = tid & 31;
    const float* Wh = W + (size_t)h * K * N;
#pragma unroll
    for (int i = 0; i < 4; ++i)
      T[(r + i * 8) * 33 + cc] = Wh[(size_t)(tk * 32 + r + i * 8) * N + tn * 32 + cc];
    __syncthreads();
    __hip_bfloat16* Bh = B + (size_t)h * N * K;
#pragma unroll
    for (int i = 0; i < 4; ++i)
      Bh[(size_t)(tn * 32 + r + i * 8) * K + tk * 32 + cc] =
          __float2bfloat16(T[cc * 33 + r + i * 8]);
  }
}

// ---------------- K2: wide BN reduce -> statsbuf = {inv[576], m*inv[576]} ---
__global__ __launch_bounds__(256) void reduce_kernel(
    const float* __restrict__ partial, float* __restrict__ statsbuf) {
  int t = blockIdx.x * 256 + threadIdx.x;
  if (t >= NFEAT) return;
  float s = 0.f, s2 = 0.f;
#pragma unroll 8
  for (int u = 0; u < 512; ++u) {
    s += partial[(size_t)u * 1152 + t];
    s2 += partial[(size_t)u * 1152 + NFEAT + t];
  }
  float m = s * (1.f / GN);
  float v = s2 * (1.f / GN) - m * m;
  float inv = rsqrtf(v + 1e-5f);
  statsbuf[t] = inv;
  statsbuf[NFEAT + t] = m * inv;
}

// ---------------- K3: W1 fold-repack (576 tiles) + cvec GEMV (4 blocks) -----
// B1t[j][k] = W1[(j<512?k:576+k)][j mod 512] * inv[k]
// gbias[j]  = (j<512 ? b1[j] : 0) - sum_f minv[f]*W1[(j<512?f:576+f)][j mod 512]
__global__ __launch_bounds__(256) void wt1_kernel(
    const float* __restrict__ W1, const float* __restrict__ b1,
    const float* __restrict__ statsbuf, __hip_bfloat16* __restrict__ B1,
    float* __restrict__ gbias) {
  int u = blockIdx.x;
  int tid = threadIdx.x;
  if (u < 576) {                        // fold-repack tile
    __shared__ float T[32 * 33];
    int jt = u / 18, kt = u - jt * 18;
    int j0 = jt * 32, k0 = kt * 32;
    int h = (j0 >= 512) ? 1 : 0;
    const float* Wh = W1 + (size_t)(h * 576) * 512 + (j0 - h * 512);
    int r = tid >> 5, cc = tid & 31;
#pragma unroll
    for (int i = 0; i < 4; ++i)
      T[(r + i * 8) * 33 + cc] = Wh[(size_t)(k0 + r + i * 8) * 512 + cc];
    __syncthreads();
    float invv = statsbuf[k0 + cc];     // k index in write phase is cc
#pragma unroll
    for (int i = 0; i < 4; ++i)
      B1[(size_t)(j0 + r + i * 8) * 576 + k0 + cc] =
          __float2bfloat16(T[cc * 33 + (r + i * 8)] * invv);
  } else {                              // cvec GEMV
    int j = (u - 576) * 256 + tid;      // 0..1023
    int col = (j < 512) ? j : j - 512;
    const float* base = W1 + (size_t)((j < 512) ? 0 : 576) * 512 + col;
    float s = 0.f;
#pragma unroll 4
    for (int f = 0; f < NFEAT; ++f) s += statsbuf[NFEAT + f] * base[(size_t)f * 512];
    gbias[j] = ((j < 512) ? b1[j] : 0.f) - s;
  }
}

// ---------------- MFMA bf16 GEMM: P = x @ Bt^T (+bias on cols < biasN) ------
// 128x128 tile, 4 waves 2x2, 2-phase double-buffered LDS (BK=32), supergroup
// swizzle: 8 m-tiles round-robin per supergroup, n-tiles walked locally.
__global__ __launch_bounds__(256) void gemm_kernel(
    const __hip_bfloat16* __restrict__ Xptr, const __hip_bfloat16* __restrict__ Bt,
    const float* __restrict__ bias, int biasN,
    __hip_bfloat16* __restrict__ Pptr, int Np, int K, int NTN) {
  __shared__ short Ash[2][128 * 32];
  __shared__ short Bsh[2][128 * 32];
  int tid = threadIdx.x;

  int bid = blockIdx.x;
  int sg = bid / (NTN * 8);
  int rem = bid - sg * (NTN * 8);
  int Wm = NTM - sg * 8; if (Wm > 8) Wm = 8;
  int mt = sg * 8 + rem % Wm;
  int nt = rem / Wm;
  int m0 = mt * 128, n0 = nt * 128;

  int wave = tid >> 6, lane = tid & 63;
  int wm = wave >> 1, wn = wave & 1;
  int lr = lane & 15, kb = lane >> 4;

  f32x4 acc[4][4];
#pragma unroll
  for (int m = 0; m < 4; ++m)
#pragma unroll
    for (int n = 0; n < 4; ++n) acc[m][n] = (f32x4){0.f, 0.f, 0.f, 0.f};

  const short* Ag = (const short*)Xptr + (size_t)m0 * K;
  const short* Bg = (const short*)Bt + (size_t)n0 * K;

  int c0 = tid, c1 = tid + 256;
  int ar0 = c0 >> 2, ac0 = (c0 & 3) * 8;
  int ar1 = c1 >> 2, ac1 = (c1 & 3) * 8;

  gl_lds16(Ag + (size_t)ar0 * K + ac0, &Ash[0][c0 * 8]);
  gl_lds16(Ag + (size_t)ar1 * K + ac1, &Ash[0][c1 * 8]);
  gl_lds16(Bg + (size_t)ar0 * K + ac0, &Bsh[0][c0 * 8]);
  gl_lds16(Bg + (size_t)ar1 * K + ac1, &Bsh[0][c1 * 8]);
  __syncthreads();

  int nkt = K >> 5;
  int cur = 0;
  for (int kt = 0; kt < nkt; ++kt) {
    if (kt + 1 < nkt) {
      int k1 = (kt + 1) * 32;
      gl_lds16(Ag + (size_t)ar0 * K + k1 + ac0, &Ash[cur ^ 1][c0 * 8]);
      gl_lds16(Ag + (size_t)ar1 * K + k1 + ac1, &Ash[cur ^ 1][c1 * 8]);
      gl_lds16(Bg + (size_t)ar0 * K + k1 + ac0, &Bsh[cur ^ 1][c0 * 8]);
      gl_lds16(Bg + (size_t)ar1 * K + k1 + ac1, &Bsh[cur ^ 1][c1 * 8]);
    }
    s16x8 af[4], bfr[4];
#pragma unroll
    for (int m = 0; m < 4; ++m)
      af[m] = *(const s16x8*)&Ash[cur][(wm * 64 + m * 16 + lr) * 32 + kb * 8];
#pragma unroll
    for (int n = 0; n < 4; ++n)
      bfr[n] = *(const s16x8*)&Bsh[cur][(wn * 64 + n * 16 + lr) * 32 + kb * 8];
#pragma unroll
    for (int m = 0; m < 4; ++m)
#pragma unroll
      for (int n = 0; n < 4; ++n)
        acc[m][n] = __builtin_amdgcn_mfma_f32_16x16x32_bf16(af[m], bfr[n], acc[m][n], 0, 0, 0);
    __syncthreads();
    cur ^= 1;
  }

  int rbase = (lane >> 4) * 4;
#pragma unroll
  for (int m = 0; m < 4; ++m) {
    int row = m0 + wm * 64 + m * 16 + rbase;
#pragma unroll
    for (int n = 0; n < 4; ++n) {
      int col = n0 + wn * 64 + n * 16 + lr;
      float bv = (col < biasN) ? bias[col] : 0.f;
#pragma unroll
      for (int r = 0; r < 4; ++r) {
        float v = acc[m][n][r] + bv;
        Pptr[(size_t)(row + r) * Np + col] = __float2bfloat16(v);
      }
    }
  }
}

// ---------------- fused agg epilogue: y = relu(P_L + A @ P_R), L1-L3 --------
template <int N>
__global__ __launch_bounds__(256) void aggep_kernel(
    const __hip_bfloat16* __restrict__ P, const float* __restrict__ Aadj,
    __hip_bfloat16* __restrict__ Y) {
  constexpr int GPB = (N >= 256) ? 1 : (256 / N);
  __shared__ float Ash[GPB * NNODE * NNODE];
  int g0 = blockIdx.x * GPB;
  for (int i = threadIdx.x; i < GPB * NNODE * NNODE; i += 256)
    Ash[i] = Aadj[(size_t)g0 * (NNODE * NNODE) + i];
  __syncthreads();

  int sub, c;
  if constexpr (GPB == 1) { sub = 0; c = threadIdx.x; }
  else { sub = threadIdx.x / N; c = threadIdx.x % N; }
  const float* Am = &Ash[sub * NNODE * NNODE];
  const __hip_bfloat16* Pg = P + (size_t)(g0 + sub) * NNODE * (2 * N);
  __hip_bfloat16* Yg = Y + (size_t)(g0 + sub) * NNODE * N;

  for (; c < N; c += 256) {
    float pr[NNODE];
#pragma unroll
    for (int m = 0; m < NNODE; ++m)
      pr[m] = __bfloat162float(Pg[(size_t)m * (2 * N) + N + c]);
#pragma unroll 1
    for (int n = 0; n < NNODE; ++n) {
      float aa = __bfloat162float(Pg[(size_t)n * (2 * N) + c]);
#pragma unroll
      for (int m = 0; m < NNODE; ++m) aa += Am[n * NNODE + m] * pr[m];
      aa = aa > 0.f ? aa : 0.f;
      Yg[(size_t)n * N + c] = __float2bfloat16(aa);
    }
    if constexpr (GPB > 1) break;
  }
}

// ---------------- G4F: gemm4 + agg4 + knn classifier, 3 graphs/block --------
// X: 20992x128 bf16; B4t: 128x128 bf16; P lives only in LDS.
__global__ __launch_bounds__(256) void gemm4cls_kernel(
    const __hip_bfloat16* __restrict__ X, const __hip_bfloat16* __restrict__ B4t,
    const float* __restrict__ b4, const float* __restrict__ Aadj,
    const int* __restrict__ knn, const float* __restrict__ w1,
    const float* __restrict__ cb1, const float* __restrict__ pa,
    const float* __restrict__ w2, const float* __restrict__ cb2,
    float* __restrict__ out) {
  // LDS: [0,16384) A dbuf (2x128x32 short); [16384,49152) Bsh (4 ktiles x 128x32)
  //      Psh overlays [0,32768) after GEMM; Aash/Ysh/Wsh/cb above 49152.
  __shared__ __align__(16) char smem[49152 + 20172 + 31488 + 8192 + 520];
  short* AshD = (short*)smem;
  short* Bsh  = (short*)(smem + 16384);
  __hip_bfloat16* Psh = (__hip_bfloat16*)smem;
  float* Aash = (float*)(smem + 49152);
  float* Ysh  = (float*)(smem + 49152 + 20172);
  float* Wsh  = (float*)(smem + 49152 + 20172 + 31488);
  float* cb   = (float*)(smem + 49152 + 20172 + 31488 + 8192);

  int tid = threadIdx.x;
  int blk = blockIdx.x;
  int g0 = blk * 3;
  int gcnt = NGRAPH - g0; if (gcnt > 3) gcnt = 3;
  int row0 = blk * 123;

  // small-table loads (ordinary LDS stores, complete before first barrier)
  for (int i = tid; i < gcnt * NNODE * NNODE; i += 256)
    Aash[i] = Aadj[(size_t)g0 * (NNODE * NNODE) + i];
  for (int i = tid; i < 2048; i += 256) Wsh[i] = w1[i];
  if (tid < 32) { cb[tid] = cb1[tid]; cb[32 + tid] = pa[tid]; }
  if (tid < 64) cb[64 + tid] = w2[tid];
  if (tid < 2) cb[128 + tid] = cb2[tid];

  // stage whole B4t into 4 k-step tiles: Bsh[kt][r][kcol8]
#pragma unroll
  for (int i = 0; i < 8; ++i) {
    int c = tid + i * 256;              // 2048 chunks of 16B
    int kt = c >> 9, w = c & 511;
    int r = w >> 2, c8 = (w & 3) * 8;
    gl_lds16((const short*)B4t + (size_t)r * 128 + kt * 32 + c8, &Bsh[c * 8]);
  }
  // stage A k-tile 0
  const short* Ag = (const short*)X;
  int c0 = tid, c1 = tid + 256;
  int ar0 = c0 >> 2, ac0 = (c0 & 3) * 8;
  int ar1 = c1 >> 2, ac1 = (c1 & 3) * 8;
  int grow0 = row0 + ar0; if (grow0 > GN - 1) grow0 = GN - 1;
  int grow1 = row0 + ar1; if (grow1 > GN - 1) grow1 = GN - 1;
  gl_lds16(Ag + (size_t)grow0 * 128 + ac0, &AshD[c0 * 8]);
  gl_lds16(Ag + (size_t)grow1 * 128 + ac1, &AshD[c1 * 8]);
  __syncthreads();

  int wave = tid >> 6, lane = tid & 63;
  int wm = wave >> 1, wn = wave & 1;
  int lr = lane & 15, kb = lane >> 4;
  f32x4 acc[4][4];
#pragma unroll
  for (int m = 0; m < 4; ++m)
#pragma unroll
    for (int n = 0; n < 4; ++n) acc[m][n] = (f32x4){0.f, 0.f, 0.f, 0.f};

  int cur = 0;
  for (int kt = 0; kt < 4; ++kt) {
    if (kt < 3) {
      int k1 = (kt + 1) * 32;
      int nxt = (cur ^ 1) * 4096;
      gl_lds16(Ag + (size_t)grow0 * 128 + k1 + ac0, &AshD[nxt + c0 * 8]);
      gl_lds16(Ag + (size_t)grow1 * 128 + k1 + ac1, &AshD[nxt + c1 * 8]);
    }
    int cbse = cur * 4096;
    s16x8 af[4], bfr[4];
#pragma unroll
    for (int m = 0; m < 4; ++m)
      af[m] = *(const s16x8*)&AshD[cbse + (wm * 64 + m * 16 + lr) * 32 + kb * 8];
#pragma unroll
    for (int n = 0; n < 4; ++n)
      bfr[n] = *(const s16x8*)&Bsh[kt * 4096 + (wn * 64 + n * 16 + lr) * 32 + kb * 8];
#pragma unroll
    for (int m = 0; m < 4; ++m)
#pragma unroll
      for (int n = 0; n < 4; ++n)
        acc[m][n] = __builtin_amdgcn_mfma_f32_16x16x32_bf16(af[m], bfr[n], acc[m][n], 0, 0, 0);
    __syncthreads();   // prefetch done AND all reads of cur done
    cur ^= 1;
  }
  // epilogue -> Psh (overlays staging LDS; safe after the barrier above)
  int rbase = (lane >> 4) * 4;
#pragma unroll
  for (int m = 0; m < 4; ++m) {
    int lrow = wm * 64 + m * 16 + rbase;
#pragma unroll
    for (int n = 0; n < 4; ++n) {
      int col = wn * 64 + n * 16 + lr;
      float bv = (col < 64) ? b4[col] : 0.f;
#pragma unroll
      for (int r = 0; r < 4; ++r)
        Psh[(size_t)(lrow + r) * 128 + col] = __float2bfloat16(acc[m][n][r] + bv);
    }
  }
  __syncthreads();

  // agg: y[g][n][c] = relu(P[g*41+n][c] + sum_m A[g][n][m] * P[g*41+m][64+c])
  int c = tid & 63, grp = tid >> 6;
  for (int g = 0; g < gcnt; ++g) {
    float pr[NNODE];
    const __hip_bfloat16* Pb = Psh;
#pragma unroll
    for (int m = 0; m < NNODE; ++m)
      pr[m] = __bfloat162float(Pb[(size_t)(g * NNODE + m) * 128 + 64 + c]);
    const float* Am = Aash + g * NNODE * NNODE;
#pragma unroll 1
    for (int n = grp; n < NNODE; n += 4) {
      float aa = __bfloat162float(Pb[(size_t)(g * NNODE + n) * 128 + c]);
#pragma unroll
      for (int m = 0; m < NNODE; ++m) aa += Am[n * NNODE + m] * pr[m];
      Ysh[(g * NNODE + n) * 64 + c] = aa > 0.f ? aa : 0.f;
    }
  }
  __syncthreads();

  // classifier: 8*gcnt edges, 32 lanes each
  int j = tid & 31, slot = tid >> 5;
  for (int el = slot; el < 8 * gcnt; el += 8) {
    int e = g0 * 8 + el;
    int node = knn[e];
    int gl = el >> 3;
    const float* fp = &Ysh[(gl * NNODE + node) * 64];
    float a2 = cb[j];
#pragma unroll
    for (int d = 0; d < 64; ++d) a2 += fp[d] * Wsh[d * 32 + j];
    float h = a2 >= 0.f ? a2 : cb[32 + j] * a2;
#pragma unroll
    for (int o = 0; o < 2; ++o) {
      float v = h * cb[64 + j * 2 + o];
      v += __shfl_xor(v, 16, 32); v += __shfl_xor(v, 8, 32);
      v += __shfl_xor(v, 4, 32);  v += __shfl_xor(v, 2, 32);
      v += __shfl_xor(v, 1, 32);
      if (j == 0) out[(size_t)e * 2 + o] = v;
    }
  }
}

// ---------------------------------------------------------------------------
extern "C" void kernel_launch(void* const* d_in, const int* in_sizes, int n_in,
                              void* d_out, int out_size, void* d_ws, size_t ws_size,
                              hipStream_t stream) {
  const float* inputs     = (const float*)d_in[0];
  const float* node_feats = (const float*)d_in[1];
  const float* Aadj       = (const float*)d_in[2];
  const int*   knn        = (const int*)d_in[3];
  const float* conv_w     = (const float*)d_in[4];
  const float* conv_b     = (const float*)d_in[5];
  const float* W1 = (const float*)d_in[6];  const float* b1 = (const float*)d_in[7];
  const float* W2 = (const float*)d_in[8];  const float* b2 = (const float*)d_in[9];
  const float* W3 = (const float*)d_in[10]; const float* b3 = (const float*)d_in[11];
  const float* W4 = (const float*)d_in[12]; const float* b4 = (const float*)d_in[13];
  const float* cls_w1 = (const float*)d_in[14]; const float* cls_b1 = (const float*)d_in[15];
  const float* prelu_a = (const float*)d_in[16];
  const float* cls_w2 = (const float*)d_in[17]; const float* cls_b2 = (const float*)d_in[18];
  float* out = (float*)d_out;

  char* ws = (char*)d_ws;
  char* R1 = ws;                        // x0 (24.2 MB) / y1 / y2 / y3
  char* R2 = ws + 24200192;             // P1 (43.0 MB) / P2 / P3
  char* wp = ws + 24200192 + 42991616;
  __hip_bfloat16* B1t = (__hip_bfloat16*)wp;  wp += 1179648;   // 1024 x 576
  __hip_bfloat16* B2t = (__hip_bfloat16*)wp;  wp += 524288;    // 512 x 512
  __hip_bfloat16* B3t = (__hip_bfloat16*)wp;  wp += 131072;    // 256 x 256
  __hip_bfloat16* B4t = (__hip_bfloat16*)wp;  wp += 32768;     // 128 x 128
  float* partial  = (float*)wp;               wp += 512 * 1152 * 4;
  float* statsbuf = (float*)wp;               wp += 1152 * 4;
  float* gbias    = (float*)wp;               wp += 1024 * 4;

  __hip_bfloat16* x0 = (__hip_bfloat16*)R1;
  __hip_bfloat16* P1 = (__hip_bfloat16*)R2;

  // K1: conv || cast || stats || repack W2-4
  front_kernel<<<7520, 256, 0, stream>>>(inputs, conv_w, conv_b, node_feats,
                                         W2, W3, W4, out, partial, x0,
                                         B2t, B3t, B4t);
  // K2: wide BN reduce
  reduce_kernel<<<3, 256, 0, stream>>>(partial, statsbuf);
  // K3: W1 fold-repack + cvec GEMV
  wt1_kernel<<<580, 256, 0, stream>>>(W1, b1, statsbuf, B1t, gbias);

  // L1
  gemm_kernel<<<NTM * 8, 256, 0, stream>>>(x0, B1t, gbias, 1024, P1, 1024, 576, 8);
  aggep_kernel<512><<<512, 256, 0, stream>>>(P1, Aadj, (__hip_bfloat16*)R1);
  // L2
  gemm_kernel<<<NTM * 4, 256, 0, stream>>>(
      (__hip_bfloat16*)R1, B2t, b2, 256, (__hip_bfloat16*)R2, 512, 512, 4);
  aggep_kernel<256><<<512, 256, 0, stream>>>(
      (__hip_bfloat16*)R2, Aadj, (__hip_bfloat16*)R1);
  // L3
  gemm_kernel<<<NTM * 2, 256, 0, stream>>>(
      (__hip_bfloat16*)R1, B3t, b3, 128, (__hip_bfloat16*)R2, 256, 256, 2);
  aggep_kernel<128><<<256, 256, 0, stream>>>(
      (__hip_bfloat16*)R2, Aadj, (__hip_bfloat16*)R1);
  // L4 fused: gemm + agg + knn classifier
  gemm4cls_kernel<<<171, 256, 0, stream>>>(
      (__hip_bfloat16*)R1, B4t, b4, Aadj, knn, cls_w1, cls_b1, prelu_a,
      cls_w2, cls_b2, out + 6291456);
}

// Round 7
// 366.898 us; speedup vs baseline: 1.9209x; 1.0646x over previous
//
#include <hip/hip_runtime.h>
#include <hip/hip_bf16.h>

// ---------------------------------------------------------------------------
// DRRGHead, 10 regular dispatches.
//   relu(cat(x_norm, A@x_norm) @ W + b) == relu(x@W' + b' + A@(x@W'_bot))
// BN folded into W1 (rows scaled by inv) + bias (A row-normalized passes the
// constant through mean-aggregation).
// K1 front: bf16-cast || bn-stats || repack W2-4  (low-VGPR streamers only;
//           R6 lesson: merging conv here capped VGPR=28 and serialized conv)
// K2: wide bn-reduce; K3: W1 fold-repack + cvec GEMV
// G1(+conv pool): L1 MFMA GEMM, conv blocks appended to fill the grid tail
// A1,G2,A2,G3,A3: GEMM / fused agg epilogue;  G4F: gemm4+agg4+classifier.
// ---------------------------------------------------------------------------

using f32x4 = __attribute__((ext_vector_type(4))) float;
using s16x8 = __attribute__((ext_vector_type(8))) short;   // 8 bf16

#define GN 20992          // G*N rows (= 164*128 exactly)
#define NFEAT 576
#define NGRAPH 512
#define NNODE 41
#define NTM 164           // m-tiles of 128

typedef __attribute__((address_space(1))) const unsigned int gas_u32;
typedef __attribute__((address_space(3))) unsigned int las_u32;

__device__ __forceinline__ void gl_lds16(const void* g, void* l) {
  __builtin_amdgcn_global_load_lds((gas_u32*)g, (las_u32*)l, 16, 0, 0);
}

// ---------------- K1: front (cast || stats || wt2-4 pools) ------------------
__global__ __launch_bounds__(256) void front_kernel(
    const float* __restrict__ nf,
    const float* __restrict__ W2, const float* __restrict__ W3,
    const float* __restrict__ W4,
    float* __restrict__ partial, __hip_bfloat16* __restrict__ x0,
    __hip_bfloat16* __restrict__ B2, __hip_bfloat16* __restrict__ B3,
    __hip_bfloat16* __restrict__ B4) {
  __shared__ float T[32 * 33];
  int b = blockIdx.x;
  int tid = threadIdx.x;
  if (b < 5904) {                       // ---- bf16 cast pool (raw x)
    int idx = b * 256 + tid;            // 8-elem chunk
    const float* src = nf + (size_t)idx * 8;
    float4 p0 = *(const float4*)src, p1 = *(const float4*)(src + 4);
    float vv[8] = {p0.x, p0.y, p0.z, p0.w, p1.x, p1.y, p1.z, p1.w};
    __hip_bfloat16 o[8];
#pragma unroll
    for (int j = 0; j < 8; ++j) o[j] = __float2bfloat16(vv[j]);
    *(uint4*)&x0[(size_t)idx * 8] = *(const uint4*)o;
  } else if (b < 6160) {                // ---- bn stats pool
    int u = b - 5904;                   // 256 units x 82 rows
    int r0 = u * 82;
    for (int c = tid; c < NFEAT; c += 256) {
      float s = 0.f, s2 = 0.f;
#pragma unroll 1
      for (int r = 0; r < 82; ++r) {
        float v = nf[(size_t)(r0 + r) * NFEAT + c];
        s += v; s2 += v * v;
      }
      partial[(size_t)u * 1152 + c] = s;
      partial[(size_t)u * 1152 + NFEAT + c] = s2;
    }
  } else {                              // ---- wt repack pool (W2, W3, W4)
    int u = b - 6160;
    const float* W; __hip_bfloat16* B; int K, N, t;
    if (u < 256)      { W = W2; B = B2; K = 512; N = 256; t = u; }
    else if (u < 320) { W = W3; B = B3; K = 256; N = 128; t = u - 256; }
    else              { W = W4; B = B4; K = 128; N = 64;  t = u - 320; }
    int tilesN = N >> 5;
    int perhalf = (K >> 5) * tilesN;
    int h = t / perhalf; t -= h * perhalf;
    int tk = t / tilesN, tn = t - tk * tilesN;
    int r = tid >> 5, cc = tid & 31;
    const float* Wh = W + (size_t)h * K * N;
#pragma unroll
    for (int i = 0; i < 4; ++i)
      T[(r + i * 8) * 33 + cc] = Wh[(size_t)(tk * 32 + r + i * 8) * N + tn * 32 + cc];
    __syncthreads();
    __hip_bfloat16* Bh = B + (size_t)h * N * K;
#pragma unroll
    for (int i = 0; i < 4; ++i)
      Bh[(size_t)(tn * 32 + r + i * 8) * K + tk * 32 + cc] =
          __float2bfloat16(T[cc * 33 + r + i * 8]);
  }
}

// ---------------- K2: wide BN reduce -> statsbuf = {inv[576], m*inv[576]} ---
__global__ __launch_bounds__(256) void reduce_kernel(
    const float* __restrict__ partial, float* __restrict__ statsbuf) {
  int t = blockIdx.x * 256 + threadIdx.x;
  if (t >= NFEAT) return;
  float s = 0.f, s2 = 0.f;
#pragma unroll 8
  for (int u = 0; u < 256; ++u) {
    s += partial[(size_t)u * 1152 + t];
    s2 += partial[(size_t)u * 1152 + NFEAT + t];
  }
  float m = s * (1.f / GN);
  float v = s2 * (1.f / GN) - m * m;
  float inv = rsqrtf(v + 1e-5f);
  statsbuf[t] = inv;
  statsbuf[NFEAT + t] = m * inv;
}

// ---------------- K3: W1 fold-repack (576 tiles) + cvec GEMV (4 blocks) -----
// B1t[j][k] = W1[(j<512?k:576+k)][j mod 512] * inv[k]
// gbias[j]  = (j<512 ? b1[j] : 0) - sum_f minv[f]*W1[(j<512?f:576+f)][j mod 512]
__global__ __launch_bounds__(256) void wt1_kernel(
    const float* __restrict__ W1, const float* __restrict__ b1,
    const float* __restrict__ statsbuf, __hip_bfloat16* __restrict__ B1,
    float* __restrict__ gbias) {
  int u = blockIdx.x;
  int tid = threadIdx.x;
  if (u < 576) {                        // fold-repack tile
    __shared__ float T[32 * 33];
    int jt = u / 18, kt = u - jt * 18;
    int j0 = jt * 32, k0 = kt * 32;
    int h = (j0 >= 512) ? 1 : 0;
    const float* Wh = W1 + (size_t)(h * 576) * 512 + (j0 - h * 512);
    int r = tid >> 5, cc = tid & 31;
#pragma unroll
    for (int i = 0; i < 4; ++i)
      T[(r + i * 8) * 33 + cc] = Wh[(size_t)(k0 + r + i * 8) * 512 + cc];
    __syncthreads();
    float invv = statsbuf[k0 + cc];     // k index in write phase is cc
#pragma unroll
    for (int i = 0; i < 4; ++i)
      B1[(size_t)(j0 + r + i * 8) * 576 + k0 + cc] =
          __float2bfloat16(T[cc * 33 + (r + i * 8)] * invv);
  } else {                              // cvec GEMV
    int j = (u - 576) * 256 + tid;      // 0..1023
    int col = (j < 512) ? j : j - 512;
    const float* base = W1 + (size_t)((j < 512) ? 0 : 576) * 512 + col;
    float s = 0.f;
#pragma unroll 4
    for (int f = 0; f < NFEAT; ++f) s += statsbuf[NFEAT + f] * base[(size_t)f * 512];
    gbias[j] = ((j < 512) ? b1[j] : 0.f) - s;
  }
}

// ---------------- MFMA bf16 GEMM: P = x @ Bt^T (+bias on cols < biasN) ------
// 128x128 tile, 4 waves 2x2, 2-phase double-buffered LDS (BK=32), supergroup
// swizzle. Blocks beyond the GEMM grid run the 1x1-conv pool (fills the tail).
__global__ __launch_bounds__(256) void gemm_kernel(
    const __hip_bfloat16* __restrict__ Xptr, const __hip_bfloat16* __restrict__ Bt,
    const float* __restrict__ bias, int biasN,
    __hip_bfloat16* __restrict__ Pptr, int Np, int K, int NTN,
    const float* __restrict__ cinputs, const float* __restrict__ conv_w,
    const float* __restrict__ conv_b, float* __restrict__ cout) {
  __shared__ short Ash[2][128 * 32];
  __shared__ short Bsh[2][128 * 32];
  int tid = threadIdx.x;
  int bid = blockIdx.x;
  int gemmBlocks = NTM * NTN;

  if (bid >= gemmBlocks) {              // ---- conv pool (tail filler)
    int p = (bid - gemmBlocks) * 256 + tid;
    int img = p >> 16, q = p & 65535;
    const float4* ip = (const float4*)cinputs + (size_t)img * 32 * 65536 + q;
    float4 acc[6];
#pragma unroll
    for (int o = 0; o < 6; ++o) { float b0 = conv_b[o]; acc[o] = make_float4(b0, b0, b0, b0); }
#pragma unroll 4
    for (int c = 0; c < 32; ++c) {
      float4 x = ip[(size_t)c * 65536];
#pragma unroll
      for (int o = 0; o < 6; ++o) {
        float wv = conv_w[o * 32 + c];
        acc[o].x += x.x * wv; acc[o].y += x.y * wv;
        acc[o].z += x.z * wv; acc[o].w += x.w * wv;
      }
    }
    float4* op = (float4*)cout + (size_t)img * 6 * 65536 + q;
#pragma unroll
    for (int o = 0; o < 6; ++o) op[(size_t)o * 65536] = acc[o];
    return;
  }

  int sg = bid / (NTN * 8);
  int rem = bid - sg * (NTN * 8);
  int Wm = NTM - sg * 8; if (Wm > 8) Wm = 8;
  int mt = sg * 8 + rem % Wm;
  int nt = rem / Wm;
  int m0 = mt * 128, n0 = nt * 128;

  int wave = tid >> 6, lane = tid & 63;
  int wm = wave >> 1, wn = wave & 1;
  int lr = lane & 15, kb = lane >> 4;

  f32x4 acc[4][4];
#pragma unroll
  for (int m = 0; m < 4; ++m)
#pragma unroll
    for (int n = 0; n < 4; ++n) acc[m][n] = (f32x4){0.f, 0.f, 0.f, 0.f};

  const short* Ag = (const short*)Xptr + (size_t)m0 * K;
  const short* Bg = (const short*)Bt + (size_t)n0 * K;

  int c0 = tid, c1 = tid + 256;
  int ar0 = c0 >> 2, ac0 = (c0 & 3) * 8;
  int ar1 = c1 >> 2, ac1 = (c1 & 3) * 8;

  gl_lds16(Ag + (size_t)ar0 * K + ac0, &Ash[0][c0 * 8]);
  gl_lds16(Ag + (size_t)ar1 * K + ac1, &Ash[0][c1 * 8]);
  gl_lds16(Bg + (size_t)ar0 * K + ac0, &Bsh[0][c0 * 8]);
  gl_lds16(Bg + (size_t)ar1 * K + ac1, &Bsh[0][c1 * 8]);
  __syncthreads();

  int nkt = K >> 5;
  int cur = 0;
  for (int kt = 0; kt < nkt; ++kt) {
    if (kt + 1 < nkt) {
      int k1 = (kt + 1) * 32;
      gl_lds16(Ag + (size_t)ar0 * K + k1 + ac0, &Ash[cur ^ 1][c0 * 8]);
      gl_lds16(Ag + (size_t)ar1 * K + k1 + ac1, &Ash[cur ^ 1][c1 * 8]);
      gl_lds16(Bg + (size_t)ar0 * K + k1 + ac0, &Bsh[cur ^ 1][c0 * 8]);
      gl_lds16(Bg + (size_t)ar1 * K + k1 + ac1, &Bsh[cur ^ 1][c1 * 8]);
    }
    s16x8 af[4], bfr[4];
#pragma unroll
    for (int m = 0; m < 4; ++m)
      af[m] = *(const s16x8*)&Ash[cur][(wm * 64 + m * 16 + lr) * 32 + kb * 8];
#pragma unroll
    for (int n = 0; n < 4; ++n)
      bfr[n] = *(const s16x8*)&Bsh[cur][(wn * 64 + n * 16 + lr) * 32 + kb * 8];
#pragma unroll
    for (int m = 0; m < 4; ++m)
#pragma unroll
      for (int n = 0; n < 4; ++n)
        acc[m][n] = __builtin_amdgcn_mfma_f32_16x16x32_bf16(af[m], bfr[n], acc[m][n], 0, 0, 0);
    __syncthreads();
    cur ^= 1;
  }

  int rbase = (lane >> 4) * 4;
#pragma unroll
  for (int m = 0; m < 4; ++m) {
    int row = m0 + wm * 64 + m * 16 + rbase;
#pragma unroll
    for (int n = 0; n < 4; ++n) {
      int col = n0 + wn * 64 + n * 16 + lr;
      float bv = (col < biasN) ? bias[col] : 0.f;
#pragma unroll
      for (int r = 0; r < 4; ++r) {
        float v = acc[m][n][r] + bv;
        Pptr[(size_t)(row + r) * Np + col] = __float2bfloat16(v);
      }
    }
  }
}

// ---------------- fused agg epilogue: y = relu(P_L + A @ P_R), L1-L3 --------
template <int N>
__global__ __launch_bounds__(256) void aggep_kernel(
    const __hip_bfloat16* __restrict__ P, const float* __restrict__ Aadj,
    __hip_bfloat16* __restrict__ Y) {
  constexpr int GPB = (N >= 256) ? 1 : (256 / N);
  __shared__ float Ash[GPB * NNODE * NNODE];
  int g0 = blockIdx.x * GPB;
  for (int i = threadIdx.x; i < GPB * NNODE * NNODE; i += 256)
    Ash[i] = Aadj[(size_t)g0 * (NNODE * NNODE) + i];
  __syncthreads();

  int sub, c;
  if constexpr (GPB == 1) { sub = 0; c = threadIdx.x; }
  else { sub = threadIdx.x / N; c = threadIdx.x % N; }
  const float* Am = &Ash[sub * NNODE * NNODE];
  const __hip_bfloat16* Pg = P + (size_t)(g0 + sub) * NNODE * (2 * N);
  __hip_bfloat16* Yg = Y + (size_t)(g0 + sub) * NNODE * N;

  for (; c < N; c += 256) {
    float pr[NNODE];
#pragma unroll
    for (int m = 0; m < NNODE; ++m)
      pr[m] = __bfloat162float(Pg[(size_t)m * (2 * N) + N + c]);
#pragma unroll 1
    for (int n = 0; n < NNODE; ++n) {
      float aa = __bfloat162float(Pg[(size_t)n * (2 * N) + c]);
#pragma unroll
      for (int m = 0; m < NNODE; ++m) aa += Am[n * NNODE + m] * pr[m];
      aa = aa > 0.f ? aa : 0.f;
      Yg[(size_t)n * N + c] = __float2bfloat16(aa);
    }
    if constexpr (GPB > 1) break;
  }
}

// ---------------- G4F: gemm4 + agg4 + knn classifier, 3 graphs/block --------
// X: 20992x128 bf16; B4t: 128x128 bf16; P lives only in LDS.
__global__ __launch_bounds__(256) void gemm4cls_kernel(
    const __hip_bfloat16* __restrict__ X, const __hip_bfloat16* __restrict__ B4t,
    const float* __restrict__ b4, const float* __restrict__ Aadj,
    const int* __restrict__ knn, const float* __restrict__ w1,
    const float* __restrict__ cb1, const float* __restrict__ pa,
    const float* __restrict__ w2, const float* __restrict__ cb2,
    float* __restrict__ out) {
  // LDS: [0,16384) A dbuf (2x128x32 short); [16384,49152) Bsh (4 ktiles x 128x32)
  //      Psh overlays [0,32768) after GEMM; Aash/Ysh/Wsh/cb above 49152.
  __shared__ __align__(16) char smem[49152 + 20172 + 31488 + 8192 + 520];
  short* AshD = (short*)smem;
  short* Bsh  = (short*)(smem + 16384);
  __hip_bfloat16* Psh = (__hip_bfloat16*)smem;
  float* Aash = (float*)(smem + 49152);
  float* Ysh  = (float*)(smem + 49152 + 20172);
  float* Wsh  = (float*)(smem + 49152 + 20172 + 31488);
  float* cb   = (float*)(smem + 49152 + 20172 + 31488 + 8192);

  int tid = threadIdx.x;
  int blk = blockIdx.x;
  int g0 = blk * 3;
  int gcnt = NGRAPH - g0; if (gcnt > 3) gcnt = 3;
  int row0 = blk * 123;

  for (int i = tid; i < gcnt * NNODE * NNODE; i += 256)
    Aash[i] = Aadj[(size_t)g0 * (NNODE * NNODE) + i];
  for (int i = tid; i < 2048; i += 256) Wsh[i] = w1[i];
  if (tid < 32) { cb[tid] = cb1[tid]; cb[32 + tid] = pa[tid]; }
  if (tid < 64) cb[64 + tid] = w2[tid];
  if (tid < 2) cb[128 + tid] = cb2[tid];

  // stage whole B4t into 4 k-step tiles: Bsh[kt][r][kcol8]
#pragma unroll
  for (int i = 0; i < 8; ++i) {
    int c = tid + i * 256;              // 2048 chunks of 16B
    int kt = c >> 9, w = c & 511;
    int r = w >> 2, c8 = (w & 3) * 8;
    gl_lds16((const short*)B4t + (size_t)r * 128 + kt * 32 + c8, &Bsh[c * 8]);
  }
  // stage A k-tile 0
  const short* Ag = (const short*)X;
  int c0 = tid, c1 = tid + 256;
  int ar0 = c0 >> 2, ac0 = (c0 & 3) * 8;
  int ar1 = c1 >> 2, ac1 = (c1 & 3) * 8;
  int grow0 = row0 + ar0; if (grow0 > GN - 1) grow0 = GN - 1;
  int grow1 = row0 + ar1; if (grow1 > GN - 1) grow1 = GN - 1;
  gl_lds16(Ag + (size_t)grow0 * 128 + ac0, &AshD[c0 * 8]);
  gl_lds16(Ag + (size_t)grow1 * 128 + ac1, &AshD[c1 * 8]);
  __syncthreads();

  int wave = tid >> 6, lane = tid & 63;
  int wm = wave >> 1, wn = wave & 1;
  int lr = lane & 15, kb = lane >> 4;
  f32x4 acc[4][4];
#pragma unroll
  for (int m = 0; m < 4; ++m)
#pragma unroll
    for (int n = 0; n < 4; ++n) acc[m][n] = (f32x4){0.f, 0.f, 0.f, 0.f};

  int cur = 0;
  for (int kt = 0; kt < 4; ++kt) {
    if (kt < 3) {
      int k1 = (kt + 1) * 32;
      int nxt = (cur ^ 1) * 4096;
      gl_lds16(Ag + (size_t)grow0 * 128 + k1 + ac0, &AshD[nxt + c0 * 8]);
      gl_lds16(Ag + (size_t)grow1 * 128 + k1 + ac1, &AshD[nxt + c1 * 8]);
    }
    int cbse = cur * 4096;
    s16x8 af[4], bfr[4];
#pragma unroll
    for (int m = 0; m < 4; ++m)
      af[m] = *(const s16x8*)&AshD[cbse + (wm * 64 + m * 16 + lr) * 32 + kb * 8];
#pragma unroll
    for (int n = 0; n < 4; ++n)
      bfr[n] = *(const s16x8*)&Bsh[kt * 4096 + (wn * 64 + n * 16 + lr) * 32 + kb * 8];
#pragma unroll
    for (int m = 0; m < 4; ++m)
#pragma unroll
      for (int n = 0; n < 4; ++n)
        acc[m][n] = __builtin_amdgcn_mfma_f32_16x16x32_bf16(af[m], bfr[n], acc[m][n], 0, 0, 0);
    __syncthreads();   // prefetch done AND all reads of cur done
    cur ^= 1;
  }
  // epilogue -> Psh (overlays staging LDS; safe after the barrier above)
  int rbase = (lane >> 4) * 4;
#pragma unroll
  for (int m = 0; m < 4; ++m) {
    int lrow = wm * 64 + m * 16 + rbase;
#pragma unroll
    for (int n = 0; n < 4; ++n) {
      int col = wn * 64 + n * 16 + lr;
      float bv = (col < 64) ? b4[col] : 0.f;
#pragma unroll
      for (int r = 0; r < 4; ++r)
        Psh[(size_t)(lrow + r) * 128 + col] = __float2bfloat16(acc[m][n][r] + bv);
    }
  }
  __syncthreads();

  // agg: y[g][n][c] = relu(P[g*41+n][c] + sum_m A[g][n][m] * P[g*41+m][64+c])
  int c = tid & 63, grp = tid >> 6;
  for (int g = 0; g < gcnt; ++g) {
    float pr[NNODE];
    const __hip_bfloat16* Pb = Psh;
#pragma unroll
    for (int m = 0; m < NNODE; ++m)
      pr[m] = __bfloat162float(Pb[(size_t)(g * NNODE + m) * 128 + 64 + c]);
    const float* Am = Aash + g * NNODE * NNODE;
#pragma unroll 1
    for (int n = grp; n < NNODE; n += 4) {
      float aa = __bfloat162float(Pb[(size_t)(g * NNODE + n) * 128 + c]);
#pragma unroll
      for (int m = 0; m < NNODE; ++m) aa += Am[n * NNODE + m] * pr[m];
      Ysh[(g * NNODE + n) * 64 + c] = aa > 0.f ? aa : 0.f;
    }
  }
  __syncthreads();

  // classifier: 8*gcnt edges, 32 lanes each
  int j = tid & 31, slot = tid >> 5;
  for (int el = slot; el < 8 * gcnt; el += 8) {
    int e = g0 * 8 + el;
    int node = knn[e];
    int gl = el >> 3;
    const float* fp = &Ysh[(gl * NNODE + node) * 64];
    float a2 = cb[j];
#pragma unroll
    for (int d = 0; d < 64; ++d) a2 += fp[d] * Wsh[d * 32 + j];
    float h = a2 >= 0.f ? a2 : cb[32 + j] * a2;
#pragma unroll
    for (int o = 0; o < 2; ++o) {
      float v = h * cb[64 + j * 2 + o];
      v += __shfl_xor(v, 16, 32); v += __shfl_xor(v, 8, 32);
      v += __shfl_xor(v, 4, 32);  v += __shfl_xor(v, 2, 32);
      v += __shfl_xor(v, 1, 32);
      if (j == 0) out[(size_t)e * 2 + o] = v;
    }
  }
}

// ---------------------------------------------------------------------------
extern "C" void kernel_launch(void* const* d_in, const int* in_sizes, int n_in,
                              void* d_out, int out_size, void* d_ws, size_t ws_size,
                              hipStream_t stream) {
  const float* inputs     = (const float*)d_in[0];
  const float* node_feats = (const float*)d_in[1];
  const float* Aadj       = (const float*)d_in[2];
  const int*   knn        = (const int*)d_in[3];
  const float* conv_w     = (const float*)d_in[4];
  const float* conv_b     = (const float*)d_in[5];
  const float* W1 = (const float*)d_in[6];  const float* b1 = (const float*)d_in[7];
  const float* W2 = (const float*)d_in[8];  const float* b2 = (const float*)d_in[9];
  const float* W3 = (const float*)d_in[10]; const float* b3 = (const float*)d_in[11];
  const float* W4 = (const float*)d_in[12]; const float* b4 = (const float*)d_in[13];
  const float* cls_w1 = (const float*)d_in[14]; const float* cls_b1 = (const float*)d_in[15];
  const float* prelu_a = (const float*)d_in[16];
  const float* cls_w2 = (const float*)d_in[17]; const float* cls_b2 = (const float*)d_in[18];
  float* out = (float*)d_out;

  char* ws = (char*)d_ws;
  char* R1 = ws;                        // x0 (24.2 MB) / y1 / y2 / y3
  char* R2 = ws + 24200192;             // P1 (43.0 MB) / P2 / P3
  char* wp = ws + 24200192 + 42991616;
  __hip_bfloat16* B1t = (__hip_bfloat16*)wp;  wp += 1179648;   // 1024 x 576
  __hip_bfloat16* B2t = (__hip_bfloat16*)wp;  wp += 524288;    // 512 x 512
  __hip_bfloat16* B3t = (__hip_bfloat16*)wp;  wp += 131072;    // 256 x 256
  __hip_bfloat16* B4t = (__hip_bfloat16*)wp;  wp += 32768;     // 128 x 128
  float* partial  = (float*)wp;               wp += 256 * 1152 * 4;
  float* statsbuf = (float*)wp;               wp += 1152 * 4;
  float* gbias    = (float*)wp;               wp += 1024 * 4;

  __hip_bfloat16* x0 = (__hip_bfloat16*)R1;
  __hip_bfloat16* P1 = (__hip_bfloat16*)R2;

  // K1: cast || stats || repack W2-4  (6496 blocks)
  front_kernel<<<6496, 256, 0, stream>>>(node_feats, W2, W3, W4,
                                         partial, x0, B2t, B3t, B4t);
  // K2: wide BN reduce
  reduce_kernel<<<3, 256, 0, stream>>>(partial, statsbuf);
  // K3: W1 fold-repack + cvec GEMV
  wt1_kernel<<<580, 256, 0, stream>>>(W1, b1, statsbuf, B1t, gbias);

  // L1 (+ conv pool appended: 1024 blocks fill the GEMM tail)
  gemm_kernel<<<NTM * 8 + 1024, 256, 0, stream>>>(
      x0, B1t, gbias, 1024, P1, 1024, 576, 8, inputs, conv_w, conv_b, out);
  aggep_kernel<512><<<512, 256, 0, stream>>>(P1, Aadj, (__hip_bfloat16*)R1);
  // L2
  gemm_kernel<<<NTM * 4, 256, 0, stream>>>(
      (__hip_bfloat16*)R1, B2t, b2, 256, (__hip_bfloat16*)R2, 512, 512, 4,
      nullptr, nullptr, nullptr, nullptr);
  aggep_kernel<256><<<512, 256, 0, stream>>>(
      (__hip_bfloat16*)R2, Aadj, (__hip_bfloat16*)R1);
  // L3
  gemm_kernel<<<NTM * 2, 256, 0, stream>>>(
      (__hip_bfloat16*)R1, B3t, b3, 128, (__hip_bfloat16*)R2, 256, 256, 2,
      nullptr, nullptr, nullptr, nullptr);
  aggep_kernel<128><<<256, 256, 0, stream>>>(
      (__hip_bfloat16*)R2, Aadj, (__hip_bfloat16*)R1);
  // L4 fused: gemm + agg + knn classifier
  gemm4cls_kernel<<<171, 256, 0, stream>>>(
      (__hip_bfloat16*)R1, B4t, b4, Aadj, knn, cls_w1, cls_b1, prelu_a,
      cls_w2, cls_b2, out + 6291456);
}

// Round 8
// 329.249 us; speedup vs baseline: 2.1405x; 1.1143x over previous
//
#include <hip/hip_runtime.h>
#include <hip/hip_bf16.h>

// ---------------------------------------------------------------------------
// DRRGHead, 9 dispatches.
//   relu(cat(x_norm, A@x_norm) @ W + b) == relu(x@W' + b' + A@(x@W'_bot))
// BN folded into W1 (rows scaled by inv) + bias (A row-normalized passes the
// constant through mean-aggregation).
// K1 front: FUSED bf16-cast + bn-stats, one pass over nf, 576-col blocks
//           (R7 lesson: split pools with 2 loads/thread ran latency-bound at
//            550 GB/s; fused column-walk gives 82 independent loads/thread)
// K2: wide bn-reduce; K3: W1 fold-repack + cvec GEMV + W2-4 repack pools
// G1(+conv pool): L1 MFMA GEMM, conv blocks appended to fill the grid tail
// A1,G2,A2,G3,A3: GEMM / fused agg epilogue;  G4F: gemm4+agg4+classifier.
// ---------------------------------------------------------------------------

using f32x4 = __attribute__((ext_vector_type(4))) float;
using s16x8 = __attribute__((ext_vector_type(8))) short;   // 8 bf16

#define GN 20992          // G*N rows (= 164*128 = 256*82 exactly)
#define NFEAT 576
#define NGRAPH 512
#define NNODE 41
#define NTM 164           // m-tiles of 128

typedef __attribute__((address_space(1))) const unsigned int gas_u32;
typedef __attribute__((address_space(3))) unsigned int las_u32;

__device__ __forceinline__ void gl_lds16(const void* g, void* l) {
  __builtin_amdgcn_global_load_lds((gas_u32*)g, (las_u32*)l, 16, 0, 0);
}

// ---------------- K1: fused bf16-cast + bn-stats (one pass over nf) ---------
// 256 blocks x 576 threads; thread = column, block = 82 consecutive rows.
__global__ __launch_bounds__(576) void front_kernel(
    const float* __restrict__ nf, float* __restrict__ partial,
    __hip_bfloat16* __restrict__ x0) {
  int c = threadIdx.x;                  // 0..575
  int u = blockIdx.x;                   // 0..255
  int r0 = u * 82;
  const float* src = nf + (size_t)r0 * NFEAT + c;
  __hip_bfloat16* dst = x0 + (size_t)r0 * NFEAT + c;
  float s = 0.f, s2 = 0.f;
#pragma unroll 4
  for (int r = 0; r < 82; ++r) {
    float v = src[(size_t)r * NFEAT];
    s += v; s2 += v * v;
    dst[(size_t)r * NFEAT] = __float2bfloat16(v);
  }
  partial[(size_t)u * 1152 + c] = s;
  partial[(size_t)u * 1152 + NFEAT + c] = s2;
}

// ---------------- K2: wide BN reduce -> statsbuf = {inv[576], m*inv[576]} ---
__global__ __launch_bounds__(256) void reduce_kernel(
    const float* __restrict__ partial, float* __restrict__ statsbuf) {
  int t = blockIdx.x * 256 + threadIdx.x;
  if (t >= NFEAT) return;
  float s = 0.f, s2 = 0.f;
#pragma unroll 8
  for (int u = 0; u < 256; ++u) {
    s += partial[(size_t)u * 1152 + t];
    s2 += partial[(size_t)u * 1152 + NFEAT + t];
  }
  float m = s * (1.f / GN);
  float v = s2 * (1.f / GN) - m * m;
  float inv = rsqrtf(v + 1e-5f);
  statsbuf[t] = inv;
  statsbuf[NFEAT + t] = m * inv;
}

// ---------------- K3: W1 fold-repack + cvec GEMV + W2-4 repack --------------
// u<576: B1t[j][k] = W1[(j<512?k:576+k)][j mod 512] * inv[k]
// u in [576,580): gbias[j] = (j<512?b1[j]:0) - sum_f minv[f]*W1[...][...]
// u>=580: plain repack of W2/W3/W4 (no stats dependency).
__global__ __launch_bounds__(256) void wt1_kernel(
    const float* __restrict__ W1, const float* __restrict__ b1,
    const float* __restrict__ statsbuf, __hip_bfloat16* __restrict__ B1,
    float* __restrict__ gbias,
    const float* __restrict__ W2, const float* __restrict__ W3,
    const float* __restrict__ W4,
    __hip_bfloat16* __restrict__ B2, __hip_bfloat16* __restrict__ B3,
    __hip_bfloat16* __restrict__ B4) {
  int u = blockIdx.x;
  int tid = threadIdx.x;
  if (u < 576) {                        // fold-repack tile of W1
    __shared__ float T[32 * 33];
    int jt = u / 18, kt = u - jt * 18;
    int j0 = jt * 32, k0 = kt * 32;
    int h = (j0 >= 512) ? 1 : 0;
    const float* Wh = W1 + (size_t)(h * 576) * 512 + (j0 - h * 512);
    int r = tid >> 5, cc = tid & 31;
#pragma unroll
    for (int i = 0; i < 4; ++i)
      T[(r + i * 8) * 33 + cc] = Wh[(size_t)(k0 + r + i * 8) * 512 + cc];
    __syncthreads();
    float invv = statsbuf[k0 + cc];     // k index in write phase is cc
#pragma unroll
    for (int i = 0; i < 4; ++i)
      B1[(size_t)(j0 + r + i * 8) * 576 + k0 + cc] =
          __float2bfloat16(T[cc * 33 + (r + i * 8)] * invv);
  } else if (u < 580) {                 // cvec GEMV
    int j = (u - 576) * 256 + tid;      // 0..1023
    int col = (j < 512) ? j : j - 512;
    const float* base = W1 + (size_t)((j < 512) ? 0 : 576) * 512 + col;
    float s = 0.f;
#pragma unroll 4
    for (int f = 0; f < NFEAT; ++f) s += statsbuf[NFEAT + f] * base[(size_t)f * 512];
    gbias[j] = ((j < 512) ? b1[j] : 0.f) - s;
  } else {                              // plain repack W2/W3/W4
    __shared__ float T[32 * 33];
    int t = u - 580;
    const float* W; __hip_bfloat16* B; int K, N;
    if (t < 256)      { W = W2; B = B2; K = 512; N = 256; }
    else if (t < 320) { W = W3; B = B3; K = 256; N = 128; t -= 256; }
    else              { W = W4; B = B4; K = 128; N = 64;  t -= 320; }
    int tilesN = N >> 5;
    int perhalf = (K >> 5) * tilesN;
    int h = t / perhalf; t -= h * perhalf;
    int tk = t / tilesN, tn = t - tk * tilesN;
    int r = tid >> 5, cc = tid & 31;
    const float* Wh = W + (size_t)h * K * N;
#pragma unroll
    for (int i = 0; i < 4; ++i)
      T[(r + i * 8) * 33 + cc] = Wh[(size_t)(tk * 32 + r + i * 8) * N + tn * 32 + cc];
    __syncthreads();
    __hip_bfloat16* Bh = B + (size_t)h * N * K;
#pragma unroll
    for (int i = 0; i < 4; ++i)
      Bh[(size_t)(tn * 32 + r + i * 8) * K + tk * 32 + cc] =
          __float2bfloat16(T[cc * 33 + r + i * 8]);
  }
}

// ---------------- MFMA bf16 GEMM: P = x @ Bt^T (+bias on cols < biasN) ------
// 128x128 tile, 4 waves 2x2, 2-phase double-buffered LDS (BK=32), supergroup
// swizzle. Blocks beyond the GEMM grid run the 1x1-conv pool (fills the tail).
__global__ __launch_bounds__(256) void gemm_kernel(
    const __hip_bfloat16* __restrict__ Xptr, const __hip_bfloat16* __restrict__ Bt,
    const float* __restrict__ bias, int biasN,
    __hip_bfloat16* __restrict__ Pptr, int Np, int K, int NTN,
    const float* __restrict__ cinputs, const float* __restrict__ conv_w,
    const float* __restrict__ conv_b, float* __restrict__ cout) {
  __shared__ short Ash[2][128 * 32];
  __shared__ short Bsh[2][128 * 32];
  int tid = threadIdx.x;
  int bid = blockIdx.x;
  int gemmBlocks = NTM * NTN;

  if (bid >= gemmBlocks) {              // ---- conv pool (tail filler)
    int p = (bid - gemmBlocks) * 256 + tid;
    int img = p >> 16, q = p & 65535;
    const float4* ip = (const float4*)cinputs + (size_t)img * 32 * 65536 + q;
    float4 acc[6];
#pragma unroll
    for (int o = 0; o < 6; ++o) { float b0 = conv_b[o]; acc[o] = make_float4(b0, b0, b0, b0); }
#pragma unroll 4
    for (int c = 0; c < 32; ++c) {
      float4 x = ip[(size_t)c * 65536];
#pragma unroll
      for (int o = 0; o < 6; ++o) {
        float wv = conv_w[o * 32 + c];
        acc[o].x += x.x * wv; acc[o].y += x.y * wv;
        acc[o].z += x.z * wv; acc[o].w += x.w * wv;
      }
    }
    float4* op = (float4*)cout + (size_t)img * 6 * 65536 + q;
#pragma unroll
    for (int o = 0; o < 6; ++o) op[(size_t)o * 65536] = acc[o];
    return;
  }

  int sg = bid / (NTN * 8);
  int rem = bid - sg * (NTN * 8);
  int Wm = NTM - sg * 8; if (Wm > 8) Wm = 8;
  int mt = sg * 8 + rem % Wm;
  int nt = rem / Wm;
  int m0 = mt * 128, n0 = nt * 128;

  int wave = tid >> 6, lane = tid & 63;
  int wm = wave >> 1, wn = wave & 1;
  int lr = lane & 15, kb = lane >> 4;

  f32x4 acc[4][4];
#pragma unroll
  for (int m = 0; m < 4; ++m)
#pragma unroll
    for (int n = 0; n < 4; ++n) acc[m][n] = (f32x4){0.f, 0.f, 0.f, 0.f};

  const short* Ag = (const short*)Xptr + (size_t)m0 * K;
  const short* Bg = (const short*)Bt + (size_t)n0 * K;

  int c0 = tid, c1 = tid + 256;
  int ar0 = c0 >> 2, ac0 = (c0 & 3) * 8;
  int ar1 = c1 >> 2, ac1 = (c1 & 3) * 8;

  gl_lds16(Ag + (size_t)ar0 * K + ac0, &Ash[0][c0 * 8]);
  gl_lds16(Ag + (size_t)ar1 * K + ac1, &Ash[0][c1 * 8]);
  gl_lds16(Bg + (size_t)ar0 * K + ac0, &Bsh[0][c0 * 8]);
  gl_lds16(Bg + (size_t)ar1 * K + ac1, &Bsh[0][c1 * 8]);
  __syncthreads();

  int nkt = K >> 5;
  int cur = 0;
  for (int kt = 0; kt < nkt; ++kt) {
    if (kt + 1 < nkt) {
      int k1 = (kt + 1) * 32;
      gl_lds16(Ag + (size_t)ar0 * K + k1 + ac0, &Ash[cur ^ 1][c0 * 8]);
      gl_lds16(Ag + (size_t)ar1 * K + k1 + ac1, &Ash[cur ^ 1][c1 * 8]);
      gl_lds16(Bg + (size_t)ar0 * K + k1 + ac0, &Bsh[cur ^ 1][c0 * 8]);
      gl_lds16(Bg + (size_t)ar1 * K + k1 + ac1, &Bsh[cur ^ 1][c1 * 8]);
    }
    s16x8 af[4], bfr[4];
#pragma unroll
    for (int m = 0; m < 4; ++m)
      af[m] = *(const s16x8*)&Ash[cur][(wm * 64 + m * 16 + lr) * 32 + kb * 8];
#pragma unroll
    for (int n = 0; n < 4; ++n)
      bfr[n] = *(const s16x8*)&Bsh[cur][(wn * 64 + n * 16 + lr) * 32 + kb * 8];
#pragma unroll
    for (int m = 0; m < 4; ++m)
#pragma unroll
      for (int n = 0; n < 4; ++n)
        acc[m][n] = __builtin_amdgcn_mfma_f32_16x16x32_bf16(af[m], bfr[n], acc[m][n], 0, 0, 0);
    __syncthreads();
    cur ^= 1;
  }

  int rbase = (lane >> 4) * 4;
#pragma unroll
  for (int m = 0; m < 4; ++m) {
    int row = m0 + wm * 64 + m * 16 + rbase;
#pragma unroll
    for (int n = 0; n < 4; ++n) {
      int col = n0 + wn * 64 + n * 16 + lr;
      float bv = (col < biasN) ? bias[col] : 0.f;
#pragma unroll
      for (int r = 0; r < 4; ++r) {
        float v = acc[m][n][r] + bv;
        Pptr[(size_t)(row + r) * Np + col] = __float2bfloat16(v);
      }
    }
  }
}

// ---------------- fused agg epilogue: y = relu(P_L + A @ P_R), L1-L3 --------
template <int N>
__global__ __launch_bounds__(256) void aggep_kernel(
    const __hip_bfloat16* __restrict__ P, const float* __restrict__ Aadj,
    __hip_bfloat16* __restrict__ Y) {
  constexpr int GPB = (N >= 256) ? 1 : (256 / N);
  __shared__ float Ash[GPB * NNODE * NNODE];
  int g0 = blockIdx.x * GPB;
  for (int i = threadIdx.x; i < GPB * NNODE * NNODE; i += 256)
    Ash[i] = Aadj[(size_t)g0 * (NNODE * NNODE) + i];
  __syncthreads();

  int sub, c;
  if constexpr (GPB == 1) { sub = 0; c = threadIdx.x; }
  else { sub = threadIdx.x / N; c = threadIdx.x % N; }
  const float* Am = &Ash[sub * NNODE * NNODE];
  const __hip_bfloat16* Pg = P + (size_t)(g0 + sub) * NNODE * (2 * N);
  __hip_bfloat16* Yg = Y + (size_t)(g0 + sub) * NNODE * N;

  for (; c < N; c += 256) {
    float pr[NNODE];
#pragma unroll
    for (int m = 0; m < NNODE; ++m)
      pr[m] = __bfloat162float(Pg[(size_t)m * (2 * N) + N + c]);
#pragma unroll 1
    for (int n = 0; n < NNODE; ++n) {
      float aa = __bfloat162float(Pg[(size_t)n * (2 * N) + c]);
#pragma unroll
      for (int m = 0; m < NNODE; ++m) aa += Am[n * NNODE + m] * pr[m];
      aa = aa > 0.f ? aa : 0.f;
      Yg[(size_t)n * N + c] = __float2bfloat16(aa);
    }
    if constexpr (GPB > 1) break;
  }
}

// ---------------- G4F: gemm4 + agg4 + knn classifier, 3 graphs/block --------
// X: 20992x128 bf16; B4t: 128x128 bf16; P lives only in LDS.
__global__ __launch_bounds__(256) void gemm4cls_kernel(
    const __hip_bfloat16* __restrict__ X, const __hip_bfloat16* __restrict__ B4t,
    const float* __restrict__ b4, const float* __restrict__ Aadj,
    const int* __restrict__ knn, const float* __restrict__ w1,
    const float* __restrict__ cb1, const float* __restrict__ pa,
    const float* __restrict__ w2, const float* __restrict__ cb2,
    float* __restrict__ out) {
  // LDS: [0,16384) A dbuf (2x128x32 short); [16384,49152) Bsh (4 ktiles x 128x32)
  //      Psh overlays [0,32768) after GEMM; Aash/Ysh/Wsh/cb above 49152.
  __shared__ __align__(16) char smem[49152 + 20172 + 31488 + 8192 + 520];
  short* AshD = (short*)smem;
  short* Bsh  = (short*)(smem + 16384);
  __hip_bfloat16* Psh = (__hip_bfloat16*)smem;
  float* Aash = (float*)(smem + 49152);
  float* Ysh  = (float*)(smem + 49152 + 20172);
  float* Wsh  = (float*)(smem + 49152 + 20172 + 31488);
  float* cb   = (float*)(smem + 49152 + 20172 + 31488 + 8192);

  int tid = threadIdx.x;
  int blk = blockIdx.x;
  int g0 = blk * 3;
  int gcnt = NGRAPH - g0; if (gcnt > 3) gcnt = 3;
  int row0 = blk * 123;

  for (int i = tid; i < gcnt * NNODE * NNODE; i += 256)
    Aash[i] = Aadj[(size_t)g0 * (NNODE * NNODE) + i];
  for (int i = tid; i < 2048; i += 256) Wsh[i] = w1[i];
  if (tid < 32) { cb[tid] = cb1[tid]; cb[32 + tid] = pa[tid]; }
  if (tid < 64) cb[64 + tid] = w2[tid];
  if (tid < 2) cb[128 + tid] = cb2[tid];

  // stage whole B4t into 4 k-step tiles: Bsh[kt][r][kcol8]
#pragma unroll
  for (int i = 0; i < 8; ++i) {
    int c = tid + i * 256;              // 2048 chunks of 16B
    int kt = c >> 9, w = c & 511;
    int r = w >> 2, c8 = (w & 3) * 8;
    gl_lds16((const short*)B4t + (size_t)r * 128 + kt * 32 + c8, &Bsh[c * 8]);
  }
  // stage A k-tile 0
  const short* Ag = (const short*)X;
  int c0 = tid, c1 = tid + 256;
  int ar0 = c0 >> 2, ac0 = (c0 & 3) * 8;
  int ar1 = c1 >> 2, ac1 = (c1 & 3) * 8;
  int grow0 = row0 + ar0; if (grow0 > GN - 1) grow0 = GN - 1;
  int grow1 = row0 + ar1; if (grow1 > GN - 1) grow1 = GN - 1;
  gl_lds16(Ag + (size_t)grow0 * 128 + ac0, &AshD[c0 * 8]);
  gl_lds16(Ag + (size_t)grow1 * 128 + ac1, &AshD[c1 * 8]);
  __syncthreads();

  int wave = tid >> 6, lane = tid & 63;
  int wm = wave >> 1, wn = wave & 1;
  int lr = lane & 15, kb = lane >> 4;
  f32x4 acc[4][4];
#pragma unroll
  for (int m = 0; m < 4; ++m)
#pragma unroll
    for (int n = 0; n < 4; ++n) acc[m][n] = (f32x4){0.f, 0.f, 0.f, 0.f};

  int cur = 0;
  for (int kt = 0; kt < 4; ++kt) {
    if (kt < 3) {
      int k1 = (kt + 1) * 32;
      int nxt = (cur ^ 1) * 4096;
      gl_lds16(Ag + (size_t)grow0 * 128 + k1 + ac0, &AshD[nxt + c0 * 8]);
      gl_lds16(Ag + (size_t)grow1 * 128 + k1 + ac1, &AshD[nxt + c1 * 8]);
    }
    int cbse = cur * 4096;
    s16x8 af[4], bfr[4];
#pragma unroll
    for (int m = 0; m < 4; ++m)
      af[m] = *(const s16x8*)&AshD[cbse + (wm * 64 + m * 16 + lr) * 32 + kb * 8];
#pragma unroll
    for (int n = 0; n < 4; ++n)
      bfr[n] = *(const s16x8*)&Bsh[kt * 4096 + (wn * 64 + n * 16 + lr) * 32 + kb * 8];
#pragma unroll
    for (int m = 0; m < 4; ++m)
#pragma unroll
      for (int n = 0; n < 4; ++n)
        acc[m][n] = __builtin_amdgcn_mfma_f32_16x16x32_bf16(af[m], bfr[n], acc[m][n], 0, 0, 0);
    __syncthreads();   // prefetch done AND all reads of cur done
    cur ^= 1;
  }
  // epilogue -> Psh (overlays staging LDS; safe after the barrier above)
  int rbase = (lane >> 4) * 4;
#pragma unroll
  for (int m = 0; m < 4; ++m) {
    int lrow = wm * 64 + m * 16 + rbase;
#pragma unroll
    for (int n = 0; n < 4; ++n) {
      int col = wn * 64 + n * 16 + lr;
      float bv = (col < 64) ? b4[col] : 0.f;
#pragma unroll
      for (int r = 0; r < 4; ++r)
        Psh[(size_t)(lrow + r) * 128 + col] = __float2bfloat16(acc[m][n][r] + bv);
    }
  }
  __syncthreads();

  // agg: y[g][n][c] = relu(P[g*41+n][c] + sum_m A[g][n][m] * P[g*41+m][64+c])
  int c = tid & 63, grp = tid >> 6;
  for (int g = 0; g < gcnt; ++g) {
    float pr[NNODE];
    const __hip_bfloat16* Pb = Psh;
#pragma unroll
    for (int m = 0; m < NNODE; ++m)
      pr[m] = __bfloat162float(Pb[(size_t)(g * NNODE + m) * 128 + 64 + c]);
    const float* Am = Aash + g * NNODE * NNODE;
#pragma unroll 1
    for (int n = grp; n < NNODE; n += 4) {
      float aa = __bfloat162float(Pb[(size_t)(g * NNODE + n) * 128 + c]);
#pragma unroll
      for (int m = 0; m < NNODE; ++m) aa += Am[n * NNODE + m] * pr[m];
      Ysh[(g * NNODE + n) * 64 + c] = aa > 0.f ? aa : 0.f;
    }
  }
  __syncthreads();

  // classifier: 8*gcnt edges, 32 lanes each
  int j = tid & 31, slot = tid >> 5;
  for (int el = slot; el < 8 * gcnt; el += 8) {
    int e = g0 * 8 + el;
    int node = knn[e];
    int gl = el >> 3;
    const float* fp = &Ysh[(gl * NNODE + node) * 64];
    float a2 = cb[j];
#pragma unroll
    for (int d = 0; d < 64; ++d) a2 += fp[d] * Wsh[d * 32 + j];
    float h = a2 >= 0.f ? a2 : cb[32 + j] * a2;
#pragma unroll
    for (int o = 0; o < 2; ++o) {
      float v = h * cb[64 + j * 2 + o];
      v += __shfl_xor(v, 16, 32); v += __shfl_xor(v, 8, 32);
      v += __shfl_xor(v, 4, 32);  v += __shfl_xor(v, 2, 32);
      v += __shfl_xor(v, 1, 32);
      if (j == 0) out[(size_t)e * 2 + o] = v;
    }
  }
}

// ---------------------------------------------------------------------------
extern "C" void kernel_launch(void* const* d_in, const int* in_sizes, int n_in,
                              void* d_out, int out_size, void* d_ws, size_t ws_size,
                              hipStream_t stream) {
  const float* inputs     = (const float*)d_in[0];
  const float* node_feats = (const float*)d_in[1];
  const float* Aadj       = (const float*)d_in[2];
  const int*   knn        = (const int*)d_in[3];
  const float* conv_w     = (const float*)d_in[4];
  const float* conv_b     = (const float*)d_in[5];
  const float* W1 = (const float*)d_in[6];  const float* b1 = (const float*)d_in[7];
  const float* W2 = (const float*)d_in[8];  const float* b2 = (const float*)d_in[9];
  const float* W3 = (const float*)d_in[10]; const float* b3 = (const float*)d_in[11];
  const float* W4 = (const float*)d_in[12]; const float* b4 = (const float*)d_in[13];
  const float* cls_w1 = (const float*)d_in[14]; const float* cls_b1 = (const float*)d_in[15];
  const float* prelu_a = (const float*)d_in[16];
  const float* cls_w2 = (const float*)d_in[17]; const float* cls_b2 = (const float*)d_in[18];
  float* out = (float*)d_out;

  char* ws = (char*)d_ws;
  char* R1 = ws;                        // x0 (24.2 MB) / y1 / y2 / y3
  char* R2 = ws + 24200192;             // P1 (43.0 MB) / P2 / P3
  char* wp = ws + 24200192 + 42991616;
  __hip_bfloat16* B1t = (__hip_bfloat16*)wp;  wp += 1179648;   // 1024 x 576
  __hip_bfloat16* B2t = (__hip_bfloat16*)wp;  wp += 524288;    // 512 x 512
  __hip_bfloat16* B3t = (__hip_bfloat16*)wp;  wp += 131072;    // 256 x 256
  __hip_bfloat16* B4t = (__hip_bfloat16*)wp;  wp += 32768;     // 128 x 128
  float* partial  = (float*)wp;               wp += 256 * 1152 * 4;
  float* statsbuf = (float*)wp;               wp += 1152 * 4;
  float* gbias    = (float*)wp;               wp += 1024 * 4;

  __hip_bfloat16* x0 = (__hip_bfloat16*)R1;
  __hip_bfloat16* P1 = (__hip_bfloat16*)R2;

  // K1: fused cast + stats (one pass over node_feats)
  front_kernel<<<256, 576, 0, stream>>>(node_feats, partial, x0);
  // K2: wide BN reduce
  reduce_kernel<<<3, 256, 0, stream>>>(partial, statsbuf);
  // K3: W1 fold-repack + cvec GEMV + W2-4 repack
  wt1_kernel<<<932, 256, 0, stream>>>(W1, b1, statsbuf, B1t, gbias,
                                      W2, W3, W4, B2t, B3t, B4t);

  // L1 (+ conv pool appended: 1024 blocks fill the GEMM tail)
  gemm_kernel<<<NTM * 8 + 1024, 256, 0, stream>>>(
      x0, B1t, gbias, 1024, P1, 1024, 576, 8, inputs, conv_w, conv_b, out);
  aggep_kernel<512><<<512, 256, 0, stream>>>(P1, Aadj, (__hip_bfloat16*)R1);
  // L2
  gemm_kernel<<<NTM * 4, 256, 0, stream>>>(
      (__hip_bfloat16*)R1, B2t, b2, 256, (__hip_bfloat16*)R2, 512, 512, 4,
      nullptr, nullptr, nullptr, nullptr);
  aggep_kernel<256><<<512, 256, 0, stream>>>(
      (__hip_bfloat16*)R2, Aadj, (__hip_bfloat16*)R1);
  // L3
  gemm_kernel<<<NTM * 2, 256, 0, stream>>>(
      (__hip_bfloat16*)R1, B3t, b3, 128, (__hip_bfloat16*)R2, 256, 256, 2,
      nullptr, nullptr, nullptr, nullptr);
  aggep_kernel<128><<<256, 256, 0, stream>>>(
      (__hip_bfloat16*)R2, Aadj, (__hip_bfloat16*)R1);
  // L4 fused: gemm + agg + knn classifier
  gemm4cls_kernel<<<171, 256, 0, stream>>>(
      (__hip_bfloat16*)R1, B4t, b4, Aadj, knn, cls_w1, cls_b1, prelu_a,
      cls_w2, cls_b2, out + 6291456);
}

// Round 9
// 328.298 us; speedup vs baseline: 2.1467x; 1.0029x over previous
//
#include <hip/hip_runtime.h>
#include <hip/hip_bf16.h>

// ---------------------------------------------------------------------------
// DRRGHead, 9 dispatches.
//   relu(cat(x_norm, A@x_norm) @ W + b) == relu(x@W' + b' + A@(x@W'_bot))
// BN folded into W1; K1 fused cast+stats; K3 all weight repacks.
// GEMM: 128x128 MFMA tile, 2-ph dbuf global_load_lds, supergroup swizzle,
//   and (R8) LDS slot-swizzle slot(row,kb)=row*4+(((row>>1)&3)^kb) applied
//   via pre-swizzled GLOBAL source (linear LDS dest) -> conflict-free
//   ds_read_b128 (was 8-way, 3.0M conflicts/dispatch).
// G4F: gemm4+agg4+classifier fused, P in LDS only.
// ---------------------------------------------------------------------------

using f32x4 = __attribute__((ext_vector_type(4))) float;
using s16x8 = __attribute__((ext_vector_type(8))) short;   // 8 bf16

#define GN 20992          // G*N rows (= 164*128 = 256*82 exactly)
#define NFEAT 576
#define NGRAPH 512
#define NNODE 41
#define NTM 164           // m-tiles of 128

typedef __attribute__((address_space(1))) const unsigned int gas_u32;
typedef __attribute__((address_space(3))) unsigned int las_u32;

__device__ __forceinline__ void gl_lds16(const void* g, void* l) {
  __builtin_amdgcn_global_load_lds((gas_u32*)g, (las_u32*)l, 16, 0, 0);
}

// ---------------- K1: fused bf16-cast + bn-stats (one pass over nf) ---------
__global__ __launch_bounds__(576) void front_kernel(
    const float* __restrict__ nf, float* __restrict__ partial,
    __hip_bfloat16* __restrict__ x0) {
  int c = threadIdx.x;                  // 0..575
  int u = blockIdx.x;                   // 0..255
  int r0 = u * 82;
  const float* src = nf + (size_t)r0 * NFEAT + c;
  __hip_bfloat16* dst = x0 + (size_t)r0 * NFEAT + c;
  float s = 0.f, s2 = 0.f;
#pragma unroll 4
  for (int r = 0; r < 82; ++r) {
    float v = src[(size_t)r * NFEAT];
    s += v; s2 += v * v;
    dst[(size_t)r * NFEAT] = __float2bfloat16(v);
  }
  partial[(size_t)u * 1152 + c] = s;
  partial[(size_t)u * 1152 + NFEAT + c] = s2;
}

// ---------------- K2: wide BN reduce -> statsbuf = {inv[576], m*inv[576]} ---
__global__ __launch_bounds__(256) void reduce_kernel(
    const float* __restrict__ partial, float* __restrict__ statsbuf) {
  int t = blockIdx.x * 256 + threadIdx.x;
  if (t >= NFEAT) return;
  float s = 0.f, s2 = 0.f;
#pragma unroll 8
  for (int u = 0; u < 256; ++u) {
    s += partial[(size_t)u * 1152 + t];
    s2 += partial[(size_t)u * 1152 + NFEAT + t];
  }
  float m = s * (1.f / GN);
  float v = s2 * (1.f / GN) - m * m;
  float inv = rsqrtf(v + 1e-5f);
  statsbuf[t] = inv;
  statsbuf[NFEAT + t] = m * inv;
}

// ---------------- K3: W1 fold-repack + cvec GEMV + W2-4 repack --------------
__global__ __launch_bounds__(256) void wt1_kernel(
    const float* __restrict__ W1, const float* __restrict__ b1,
    const float* __restrict__ statsbuf, __hip_bfloat16* __restrict__ B1,
    float* __restrict__ gbias,
    const float* __restrict__ W2, const float* __restrict__ W3,
    const float* __restrict__ W4,
    __hip_bfloat16* __restrict__ B2, __hip_bfloat16* __restrict__ B3,
    __hip_bfloat16* __restrict__ B4) {
  int u = blockIdx.x;
  int tid = threadIdx.x;
  if (u < 576) {                        // fold-repack tile of W1
    __shared__ float T[32 * 33];
    int jt = u / 18, kt = u - jt * 18;
    int j0 = jt * 32, k0 = kt * 32;
    int h = (j0 >= 512) ? 1 : 0;
    const float* Wh = W1 + (size_t)(h * 576) * 512 + (j0 - h * 512);
    int r = tid >> 5, cc = tid & 31;
#pragma unroll
    for (int i = 0; i < 4; ++i)
      T[(r + i * 8) * 33 + cc] = Wh[(size_t)(k0 + r + i * 8) * 512 + cc];
    __syncthreads();
    float invv = statsbuf[k0 + cc];
#pragma unroll
    for (int i = 0; i < 4; ++i)
      B1[(size_t)(j0 + r + i * 8) * 576 + k0 + cc] =
          __float2bfloat16(T[cc * 33 + (r + i * 8)] * invv);
  } else if (u < 580) {                 // cvec GEMV
    int j = (u - 576) * 256 + tid;      // 0..1023
    int col = (j < 512) ? j : j - 512;
    const float* base = W1 + (size_t)((j < 512) ? 0 : 576) * 512 + col;
    float s = 0.f;
#pragma unroll 4
    for (int f = 0; f < NFEAT; ++f) s += statsbuf[NFEAT + f] * base[(size_t)f * 512];
    gbias[j] = ((j < 512) ? b1[j] : 0.f) - s;
  } else {                              // plain repack W2/W3/W4
    __shared__ float T[32 * 33];
    int t = u - 580;
    const float* W; __hip_bfloat16* B; int K, N;
    if (t < 256)      { W = W2; B = B2; K = 512; N = 256; }
    else if (t < 320) { W = W3; B = B3; K = 256; N = 128; t -= 256; }
    else              { W = W4; B = B4; K = 128; N = 64;  t -= 320; }
    int tilesN = N >> 5;
    int perhalf = (K >> 5) * tilesN;
    int h = t / perhalf; t -= h * perhalf;
    int tk = t / tilesN, tn = t - tk * tilesN;
    int r = tid >> 5, cc = tid & 31;
    const float* Wh = W + (size_t)h * K * N;
#pragma unroll
    for (int i = 0; i < 4; ++i)
      T[(r + i * 8) * 33 + cc] = Wh[(size_t)(tk * 32 + r + i * 8) * N + tn * 32 + cc];
    __syncthreads();
    __hip_bfloat16* Bh = B + (size_t)h * N * K;
#pragma unroll
    for (int i = 0; i < 4; ++i)
      Bh[(size_t)(tn * 32 + r + i * 8) * K + tk * 32 + cc] =
          __float2bfloat16(T[cc * 33 + r + i * 8]);
  }
}

// ---------------- MFMA bf16 GEMM: P = x @ Bt^T (+bias on cols < biasN) ------
// LDS slot-swizzle: chunk slot(row,kb) = row*4 + (((row>>1)&3)^kb); staged by
// permuting the GLOBAL source (LDS dest linear), read with the same involution.
__global__ __launch_bounds__(256) void gemm_kernel(
    const __hip_bfloat16* __restrict__ Xptr, const __hip_bfloat16* __restrict__ Bt,
    const float* __restrict__ bias, int biasN,
    __hip_bfloat16* __restrict__ Pptr, int Np, int K, int NTN,
    const float* __restrict__ cinputs, const float* __restrict__ conv_w,
    const float* __restrict__ conv_b, float* __restrict__ cout) {
  __shared__ short Ash[2][128 * 32];
  __shared__ short Bsh[2][128 * 32];
  int tid = threadIdx.x;
  int bid = blockIdx.x;
  int gemmBlocks = NTM * NTN;

  if (bid >= gemmBlocks) {              // ---- conv pool (tail filler)
    int p = (bid - gemmBlocks) * 256 + tid;
    int img = p >> 16, q = p & 65535;
    const float4* ip = (const float4*)cinputs + (size_t)img * 32 * 65536 + q;
    float4 acc[6];
#pragma unroll
    for (int o = 0; o < 6; ++o) { float b0 = conv_b[o]; acc[o] = make_float4(b0, b0, b0, b0); }
#pragma unroll 4
    for (int c = 0; c < 32; ++c) {
      float4 x = ip[(size_t)c * 65536];
#pragma unroll
      for (int o = 0; o < 6; ++o) {
        float wv = conv_w[o * 32 + c];
        acc[o].x += x.x * wv; acc[o].y += x.y * wv;
        acc[o].z += x.z * wv; acc[o].w += x.w * wv;
      }
    }
    float4* op = (float4*)cout + (size_t)img * 6 * 65536 + q;
#pragma unroll
    for (int o = 0; o < 6; ++o) op[(size_t)o * 65536] = acc[o];
    return;
  }

  int sg = bid / (NTN * 8);
  int rem = bid - sg * (NTN * 8);
  int Wm = NTM - sg * 8; if (Wm > 8) Wm = 8;
  int mt = sg * 8 + rem % Wm;
  int nt = rem / Wm;
  int m0 = mt * 128, n0 = nt * 128;

  int wave = tid >> 6, lane = tid & 63;
  int wm = wave >> 1, wn = wave & 1;
  int lr = lane & 15, kb = lane >> 4;

  f32x4 acc[4][4];
#pragma unroll
  for (int m = 0; m < 4; ++m)
#pragma unroll
    for (int n = 0; n < 4; ++n) acc[m][n] = (f32x4){0.f, 0.f, 0.f, 0.f};

  const short* Ag = (const short*)Xptr + (size_t)m0 * K;
  const short* Bg = (const short*)Bt + (size_t)n0 * K;

  // staging: slot c holds global chunk (row = c>>2, k-chunk = (c&3)^((row>>1)&3))
  int c0 = tid, c1 = tid + 256;
  int ar0 = c0 >> 2, ak0 = (((c0 & 3) ^ ((ar0 >> 1) & 3))) * 8;
  int ar1 = c1 >> 2, ak1 = (((c1 & 3) ^ ((ar1 >> 1) & 3))) * 8;

  // fragment read offsets (shorts), hoisted: row*32 + (((row>>1)&3)^kb)*8
  int aoff[4], boff[4];
#pragma unroll
  for (int m = 0; m < 4; ++m) {
    int r = wm * 64 + m * 16 + lr;
    aoff[m] = r * 32 + ((((r >> 1) & 3) ^ kb) * 8);
  }
#pragma unroll
  for (int n = 0; n < 4; ++n) {
    int r = wn * 64 + n * 16 + lr;
    boff[n] = r * 32 + ((((r >> 1) & 3) ^ kb) * 8);
  }

  gl_lds16(Ag + (size_t)ar0 * K + ak0, &Ash[0][c0 * 8]);
  gl_lds16(Ag + (size_t)ar1 * K + ak1, &Ash[0][c1 * 8]);
  gl_lds16(Bg + (size_t)ar0 * K + ak0, &Bsh[0][c0 * 8]);
  gl_lds16(Bg + (size_t)ar1 * K + ak1, &Bsh[0][c1 * 8]);
  __syncthreads();

  int nkt = K >> 5;
  int cur = 0;
  for (int kt = 0; kt < nkt; ++kt) {
    if (kt + 1 < nkt) {
      int k1 = (kt + 1) * 32;
      gl_lds16(Ag + (size_t)ar0 * K + k1 + ak0, &Ash[cur ^ 1][c0 * 8]);
      gl_lds16(Ag + (size_t)ar1 * K + k1 + ak1, &Ash[cur ^ 1][c1 * 8]);
      gl_lds16(Bg + (size_t)ar0 * K + k1 + ak0, &Bsh[cur ^ 1][c0 * 8]);
      gl_lds16(Bg + (size_t)ar1 * K + k1 + ak1, &Bsh[cur ^ 1][c1 * 8]);
    }
    s16x8 af[4], bfr[4];
#pragma unroll
    for (int m = 0; m < 4; ++m) af[m] = *(const s16x8*)&Ash[cur][aoff[m]];
#pragma unroll
    for (int n = 0; n < 4; ++n) bfr[n] = *(const s16x8*)&Bsh[cur][boff[n]];
#pragma unroll
    for (int m = 0; m < 4; ++m)
#pragma unroll
      for (int n = 0; n < 4; ++n)
        acc[m][n] = __builtin_amdgcn_mfma_f32_16x16x32_bf16(af[m], bfr[n], acc[m][n], 0, 0, 0);
    __syncthreads();
    cur ^= 1;
  }

  int rbase = (lane >> 4) * 4;
#pragma unroll
  for (int m = 0; m < 4; ++m) {
    int row = m0 + wm * 64 + m * 16 + rbase;
#pragma unroll
    for (int n = 0; n < 4; ++n) {
      int col = n0 + wn * 64 + n * 16 + lr;
      float bv = (col < biasN) ? bias[col] : 0.f;
#pragma unroll
      for (int r = 0; r < 4; ++r) {
        float v = acc[m][n][r] + bv;
        Pptr[(size_t)(row + r) * Np + col] = __float2bfloat16(v);
      }
    }
  }
}

// ---------------- fused agg epilogue: y = relu(P_L + A @ P_R), L1-L3 --------
template <int N>
__global__ __launch_bounds__(256) void aggep_kernel(
    const __hip_bfloat16* __restrict__ P, const float* __restrict__ Aadj,
    __hip_bfloat16* __restrict__ Y) {
  constexpr int GPB = (N >= 256) ? 1 : (256 / N);
  __shared__ float Ash[GPB * NNODE * NNODE];
  int g0 = blockIdx.x * GPB;
  for (int i = threadIdx.x; i < GPB * NNODE * NNODE; i += 256)
    Ash[i] = Aadj[(size_t)g0 * (NNODE * NNODE) + i];
  __syncthreads();

  int sub, c;
  if constexpr (GPB == 1) { sub = 0; c = threadIdx.x; }
  else { sub = threadIdx.x / N; c = threadIdx.x % N; }
  const float* Am = &Ash[sub * NNODE * NNODE];
  const __hip_bfloat16* Pg = P + (size_t)(g0 + sub) * NNODE * (2 * N);
  __hip_bfloat16* Yg = Y + (size_t)(g0 + sub) * NNODE * N;

  for (; c < N; c += 256) {
    float pr[NNODE];
#pragma unroll
    for (int m = 0; m < NNODE; ++m)
      pr[m] = __bfloat162float(Pg[(size_t)m * (2 * N) + N + c]);
#pragma unroll 1
    for (int n = 0; n < NNODE; ++n) {
      float aa = __bfloat162float(Pg[(size_t)n * (2 * N) + c]);
#pragma unroll
      for (int m = 0; m < NNODE; ++m) aa += Am[n * NNODE + m] * pr[m];
      aa = aa > 0.f ? aa : 0.f;
      Yg[(size_t)n * N + c] = __float2bfloat16(aa);
    }
    if constexpr (GPB > 1) break;
  }
}

// ---------------- G4F: gemm4 + agg4 + knn classifier, 3 graphs/block --------
__global__ __launch_bounds__(256) void gemm4cls_kernel(
    const __hip_bfloat16* __restrict__ X, const __hip_bfloat16* __restrict__ B4t,
    const float* __restrict__ b4, const float* __restrict__ Aadj,
    const int* __restrict__ knn, const float* __restrict__ w1,
    const float* __restrict__ cb1, const float* __restrict__ pa,
    const float* __restrict__ w2, const float* __restrict__ cb2,
    float* __restrict__ out) {
  __shared__ __align__(16) char smem[49152 + 20172 + 31488 + 8192 + 520];
  short* AshD = (short*)smem;
  short* Bsh  = (short*)(smem + 16384);
  __hip_bfloat16* Psh = (__hip_bfloat16*)smem;
  float* Aash = (float*)(smem + 49152);
  float* Ysh  = (float*)(smem + 49152 + 20172);
  float* Wsh  = (float*)(smem + 49152 + 20172 + 31488);
  float* cb   = (float*)(smem + 49152 + 20172 + 31488 + 8192);

  int tid = threadIdx.x;
  int blk = blockIdx.x;
  int g0 = blk * 3;
  int gcnt = NGRAPH - g0; if (gcnt > 3) gcnt = 3;
  int row0 = blk * 123;

  for (int i = tid; i < gcnt * NNODE * NNODE; i += 256)
    Aash[i] = Aadj[(size_t)g0 * (NNODE * NNODE) + i];
  for (int i = tid; i < 2048; i += 256) Wsh[i] = w1[i];
  if (tid < 32) { cb[tid] = cb1[tid]; cb[32 + tid] = pa[tid]; }
  if (tid < 64) cb[64 + tid] = w2[tid];
  if (tid < 2) cb[128 + tid] = cb2[tid];

  // stage whole B4t (4 ktiles), slot-swizzled within each ktile
#pragma unroll
  for (int i = 0; i < 8; ++i) {
    int c = tid + i * 256;              // 2048 chunks of 16B
    int kt = c >> 9, w = c & 511;
    int r = w >> 2, kc = ((w & 3) ^ ((r >> 1) & 3)) * 8;
    gl_lds16((const short*)B4t + (size_t)r * 128 + kt * 32 + kc, &Bsh[c * 8]);
  }
  // stage A k-tile 0 (swizzled)
  const short* Ag = (const short*)X;
  int c0 = tid, c1 = tid + 256;
  int ar0 = c0 >> 2, ak0 = (((c0 & 3) ^ ((ar0 >> 1) & 3))) * 8;
  int ar1 = c1 >> 2, ak1 = (((c1 & 3) ^ ((ar1 >> 1) & 3))) * 8;
  int grow0 = row0 + ar0; if (grow0 > GN - 1) grow0 = GN - 1;
  int grow1 = row0 + ar1; if (grow1 > GN - 1) grow1 = GN - 1;
  gl_lds16(Ag + (size_t)grow0 * 128 + ak0, &AshD[c0 * 8]);
  gl_lds16(Ag + (size_t)grow1 * 128 + ak1, &AshD[c1 * 8]);
  __syncthreads();

  int wave = tid >> 6, lane = tid & 63;
  int wm = wave >> 1, wn = wave & 1;
  int lr = lane & 15, kb = lane >> 4;
  int aoff[4], boff[4];
#pragma unroll
  for (int m = 0; m < 4; ++m) {
    int r = wm * 64 + m * 16 + lr;
    aoff[m] = r * 32 + ((((r >> 1) & 3) ^ kb) * 8);
  }
#pragma unroll
  for (int n = 0; n < 4; ++n) {
    int r = wn * 64 + n * 16 + lr;
    boff[n] = r * 32 + ((((r >> 1) & 3) ^ kb) * 8);
  }
  f32x4 acc[4][4];
#pragma unroll
  for (int m = 0; m < 4; ++m)
#pragma unroll
    for (int n = 0; n < 4; ++n) acc[m][n] = (f32x4){0.f, 0.f, 0.f, 0.f};

  int cur = 0;
  for (int kt = 0; kt < 4; ++kt) {
    if (kt < 3) {
      int k1 = (kt + 1) * 32;
      int nxt = (cur ^ 1) * 4096;
      gl_lds16(Ag + (size_t)grow0 * 128 + k1 + ak0, &AshD[nxt + c0 * 8]);
      gl_lds16(Ag + (size_t)grow1 * 128 + k1 + ak1, &AshD[nxt + c1 * 8]);
    }
    int cbse = cur * 4096;
    s16x8 af[4], bfr[4];
#pragma unroll
    for (int m = 0; m < 4; ++m) af[m] = *(const s16x8*)&AshD[cbse + aoff[m]];
#pragma unroll
    for (int n = 0; n < 4; ++n) bfr[n] = *(const s16x8*)&Bsh[kt * 4096 + boff[n]];
#pragma unroll
    for (int m = 0; m < 4; ++m)
#pragma unroll
      for (int n = 0; n < 4; ++n)
        acc[m][n] = __builtin_amdgcn_mfma_f32_16x16x32_bf16(af[m], bfr[n], acc[m][n], 0, 0, 0);
    __syncthreads();
    cur ^= 1;
  }
  // epilogue -> Psh (overlays staging LDS; safe after the barrier above)
  int rbase = (lane >> 4) * 4;
#pragma unroll
  for (int m = 0; m < 4; ++m) {
    int lrow = wm * 64 + m * 16 + rbase;
#pragma unroll
    for (int n = 0; n < 4; ++n) {
      int col = wn * 64 + n * 16 + lr;
      float bv = (col < 64) ? b4[col] : 0.f;
#pragma unroll
      for (int r = 0; r < 4; ++r)
        Psh[(size_t)(lrow + r) * 128 + col] = __float2bfloat16(acc[m][n][r] + bv);
    }
  }
  __syncthreads();

  // agg: y[g][n][c] = relu(P[g*41+n][c] + sum_m A[g][n][m] * P[g*41+m][64+c])
  int c = tid & 63, grp = tid >> 6;
  for (int g = 0; g < gcnt; ++g) {
    float pr[NNODE];
    const __hip_bfloat16* Pb = Psh;
#pragma unroll
    for (int m = 0; m < NNODE; ++m)
      pr[m] = __bfloat162float(Pb[(size_t)(g * NNODE + m) * 128 + 64 + c]);
    const float* Am = Aash + g * NNODE * NNODE;
#pragma unroll 1
    for (int n = grp; n < NNODE; n += 4) {
      float aa = __bfloat162float(Pb[(size_t)(g * NNODE + n) * 128 + c]);
#pragma unroll
      for (int m = 0; m < NNODE; ++m) aa += Am[n * NNODE + m] * pr[m];
      Ysh[(g * NNODE + n) * 64 + c] = aa > 0.f ? aa : 0.f;
    }
  }
  __syncthreads();

  // classifier: 8*gcnt edges, 32 lanes each
  int j = tid & 31, slot = tid >> 5;
  for (int el = slot; el < 8 * gcnt; el += 8) {
    int e = g0 * 8 + el;
    int node = knn[e];
    int gl = el >> 3;
    const float* fp = &Ysh[(gl * NNODE + node) * 64];
    float a2 = cb[j];
#pragma unroll
    for (int d = 0; d < 64; ++d) a2 += fp[d] * Wsh[d * 32 + j];
    float h = a2 >= 0.f ? a2 : cb[32 + j] * a2;
#pragma unroll
    for (int o = 0; o < 2; ++o) {
      float v = h * cb[64 + j * 2 + o];
      v += __shfl_xor(v, 16, 32); v += __shfl_xor(v, 8, 32);
      v += __shfl_xor(v, 4, 32);  v += __shfl_xor(v, 2, 32);
      v += __shfl_xor(v, 1, 32);
      if (j == 0) out[(size_t)e * 2 + o] = v;
    }
  }
}

// ---------------------------------------------------------------------------
extern "C" void kernel_launch(void* const* d_in, const int* in_sizes, int n_in,
                              void* d_out, int out_size, void* d_ws, size_t ws_size,
                              hipStream_t stream) {
  const float* inputs     = (const float*)d_in[0];
  const float* node_feats = (const float*)d_in[1];
  const float* Aadj       = (const float*)d_in[2];
  const int*   knn        = (const int*)d_in[3];
  const float* conv_w     = (const float*)d_in[4];
  const float* conv_b     = (const float*)d_in[5];
  const float* W1 = (const float*)d_in[6];  const float* b1 = (const float*)d_in[7];
  const float* W2 = (const float*)d_in[8];  const float* b2 = (const float*)d_in[9];
  const float* W3 = (const float*)d_in[10]; const float* b3 = (const float*)d_in[11];
  const float* W4 = (const float*)d_in[12]; const float* b4 = (const float*)d_in[13];
  const float* cls_w1 = (const float*)d_in[14]; const float* cls_b1 = (const float*)d_in[15];
  const float* prelu_a = (const float*)d_in[16];
  const float* cls_w2 = (const float*)d_in[17]; const float* cls_b2 = (const float*)d_in[18];
  float* out = (float*)d_out;

  char* ws = (char*)d_ws;
  char* R1 = ws;                        // x0 (24.2 MB) / y1 / y2 / y3
  char* R2 = ws + 24200192;             // P1 (43.0 MB) / P2 / P3
  char* wp = ws + 24200192 + 42991616;
  __hip_bfloat16* B1t = (__hip_bfloat16*)wp;  wp += 1179648;   // 1024 x 576
  __hip_bfloat16* B2t = (__hip_bfloat16*)wp;  wp += 524288;    // 512 x 512
  __hip_bfloat16* B3t = (__hip_bfloat16*)wp;  wp += 131072;    // 256 x 256
  __hip_bfloat16* B4t = (__hip_bfloat16*)wp;  wp += 32768;     // 128 x 128
  float* partial  = (float*)wp;               wp += 256 * 1152 * 4;
  float* statsbuf = (float*)wp;               wp += 1152 * 4;
  float* gbias    = (float*)wp;               wp += 1024 * 4;

  __hip_bfloat16* x0 = (__hip_bfloat16*)R1;
  __hip_bfloat16* P1 = (__hip_bfloat16*)R2;

  // K1: fused cast + stats (one pass over node_feats)
  front_kernel<<<256, 576, 0, stream>>>(node_feats, partial, x0);
  // K2: wide BN reduce
  reduce_kernel<<<3, 256, 0, stream>>>(partial, statsbuf);
  // K3: W1 fold-repack + cvec GEMV + W2-4 repack
  wt1_kernel<<<932, 256, 0, stream>>>(W1, b1, statsbuf, B1t, gbias,
                                      W2, W3, W4, B2t, B3t, B4t);

  // L1 (+ conv pool appended: 1024 blocks fill the GEMM tail)
  gemm_kernel<<<NTM * 8 + 1024, 256, 0, stream>>>(
      x0, B1t, gbias, 1024, P1, 1024, 576, 8, inputs, conv_w, conv_b, out);
  aggep_kernel<512><<<512, 256, 0, stream>>>(P1, Aadj, (__hip_bfloat16*)R1);
  // L2
  gemm_kernel<<<NTM * 4, 256, 0, stream>>>(
      (__hip_bfloat16*)R1, B2t, b2, 256, (__hip_bfloat16*)R2, 512, 512, 4,
      nullptr, nullptr, nullptr, nullptr);
  aggep_kernel<256><<<512, 256, 0, stream>>>(
      (__hip_bfloat16*)R2, Aadj, (__hip_bfloat16*)R1);
  // L3
  gemm_kernel<<<NTM * 2, 256, 0, stream>>>(
      (__hip_bfloat16*)R1, B3t, b3, 128, (__hip_bfloat16*)R2, 256, 256, 2,
      nullptr, nullptr, nullptr, nullptr);
  aggep_kernel<128><<<256, 256, 0, stream>>>(
      (__hip_bfloat16*)R2, Aadj, (__hip_bfloat16*)R1);
  // L4 fused: gemm + agg + knn classifier
  gemm4cls_kernel<<<171, 256, 0, stream>>>(
      (__hip_bfloat16*)R1, B4t, b4, Aadj, knn, cls_w1, cls_b1, prelu_a,
      cls_w2, cls_b2, out + 6291456);
}